// Round 10
// baseline (402.378 us; speedup 1.0000x reference)
//
#include <hip/hip_runtime.h>
#include <math.h>

// GraphWaveNet forward, MI355X. Round 10: residual stream h in bf16.
// R9 analysis: h fp32 traffic ~680 MB (~108us at 6.3TB/s) = ~1/3 of runtime;
// conv inputs were ALREADY bf16-rounded (tcn converts pre-MFMA), so bf16 h
// only changes residual-add precision. Everything else = R9 structure.
//   h    : [B=16, C=32, t=13, N=1024] bf16 (residual stream, in place)
//   gm   : [m=bc*Lt+tt][N] bf16 ; g12 : [b][n][256] bf16 ; adpT : [w][v] bf16
//   skipT: [b][n][s=256] bf16 ; y1 : [b][e=512][n] bf16 ; out [B,N,O] fp32

#define NBATCH 16
#define LLEN 13
#define NNODE 1024

typedef __attribute__((ext_vector_type(8))) short bf16x8;
typedef __attribute__((ext_vector_type(4))) float f32x4;
typedef __attribute__((ext_vector_type(16))) float f32x16;

#define GLOAD16(gp, lp) __builtin_amdgcn_global_load_lds( \
    (const __attribute__((address_space(1))) void*)(gp), \
    (__attribute__((address_space(3))) void*)(lp), 16, 0, 0)

static __device__ inline short f2bf(float x) {
    union { float f; unsigned u; } v; v.f = x;
    unsigned r = v.u + 0x7FFFu + ((v.u >> 16) & 1u);
    return (short)(r >> 16);
}
static __device__ inline float bf2f(short x) {
    union { unsigned u; float f; } v; v.u = ((unsigned)(unsigned short)x) << 16;
    return v.f;
}
static __device__ inline unsigned pack2bf(float lo, float hi) {
    return (unsigned)(unsigned short)f2bf(lo) | ((unsigned)(unsigned short)f2bf(hi) << 16);
}

// ---------------- prep: adp stats | start conv | weight repack ---------------
__global__ __launch_bounds__(256) void prep_kernel(
        const float* __restrict__ emb, const float* __restrict__ x,
        const float* __restrict__ start_w, const float* __restrict__ start_b,
        const float* __restrict__ skip_w, const float* __restrict__ skip_b,
        const float* __restrict__ e1w,
        float* __restrict__ mx, float* __restrict__ inv, short* __restrict__ h,
        short* __restrict__ wcat, float* __restrict__ sbcat, short* __restrict__ e1wb) {
    int bid = blockIdx.x;
    int tid = threadIdx.x;
    if (bid < 1024) {
        int v = bid;
        __shared__ float red[256];
        float ev[10];
#pragma unroll
        for (int k = 0; k < 10; ++k) ev[k] = emb[v * 10 + k];
        float sc[4];
#pragma unroll
        for (int j = 0; j < 4; ++j) {
            int w = tid + j * 256;
            float s = 0.f;
#pragma unroll
            for (int k = 0; k < 10; ++k) s += ev[k] * emb[w * 10 + k];
            sc[j] = fmaxf(s, 0.f);
        }
        float m = fmaxf(fmaxf(sc[0], sc[1]), fmaxf(sc[2], sc[3]));
        red[tid] = m;
        __syncthreads();
        for (int s = 128; s > 0; s >>= 1) {
            if (tid < s) red[tid] = fmaxf(red[tid], red[tid + s]);
            __syncthreads();
        }
        m = red[0];
        __syncthreads();
        float sum = 0.f;
#pragma unroll
        for (int j = 0; j < 4; ++j) sum += __expf(sc[j] - m);
        red[tid] = sum;
        __syncthreads();
        for (int s = 128; s > 0; s >>= 1) {
            if (tid < s) red[tid] += red[tid + s];
            __syncthreads();
        }
        if (tid == 0) { mx[v] = m; inv[v] = 1.f / red[0]; }
    } else if (bid < 1856) {
        int it = (bid - 1024) * 256 + tid;
        int n = it & 1023, rest = it >> 10;
        int t = rest % 13, b = rest / 13;
        float2 xv = *(const float2*)(x + (size_t)it * 2);
#pragma unroll
        for (int r = 0; r < 32; ++r)
            h[((b * 32 + r) * 13 + t) * 1024 + n] =
                f2bf(start_w[r * 2] * xv.x + start_w[r * 2 + 1] * xv.y + start_b[r]);
    } else {
        int idx = (bid - 1856) * 256 + tid;
        if (idx < 65536) {
            int s = idx >> 8, k = idx & 255, i = k >> 5, c = k & 31;
            wcat[idx] = f2bf(skip_w[(i * 256 + s) * 32 + c]);
        } else {
            int j = idx - 65536;
            e1wb[j] = f2bf(e1w[j]);
        }
        if (idx < 256) {
            float s = 0.f;
#pragma unroll
            for (int i = 0; i < 8; ++i) s += skip_b[i * 256 + idx];
            sbcat[idx] = s;
        }
    }
}

// ---------------- adpT[w][v] = softmax_v(relu(E E^T))[v][w] bf16 ------------
__global__ void adpT_kernel(const float* __restrict__ emb, const float* __restrict__ mx,
                            const float* __restrict__ inv, short* __restrict__ adpT) {
    int w = blockIdx.x;
    int tid = threadIdx.x;
    __shared__ float ew[10];
    if (tid < 10) ew[tid] = emb[w * 10 + tid];
    __syncthreads();
#pragma unroll
    for (int j = 0; j < 4; ++j) {
        int v = tid + j * 256;
        float s = 0.f;
#pragma unroll
        for (int k = 0; k < 10; ++k) s += ew[k] * emb[v * 10 + k];
        s = fmaxf(s, 0.f);
        adpT[w * 1024 + v] = f2bf(__expf(s - mx[v]) * inv[v]);
    }
}

// ---------------- TCN as MFMA: conv+gate+mix -> gm bf16 ----------------------
// Per wave: one (b,t), 32 nodes. conv = [W0|W1] @ [h(t-d);h(t)] (M=32,K=64),
// gate in C/D regs, relayout via shfl_xor(32), mix = Gw @ gv (K=32).
__global__ __launch_bounds__(256) void tcn_mfma(
        const short* __restrict__ h, short* __restrict__ gm,
        short* __restrict__ g12,
        const float* __restrict__ w, const float* __restrict__ bias,
        const float* __restrict__ gcnw,
        int d, int t0, int Lt, int li) {
    int tid = threadIdx.x;
    int wave = tid >> 6, lane = tid & 63;
    int m = lane & 31, hw = lane >> 5;
    int tt = blockIdx.y, t = t0 + tt, b = blockIdx.z;
    int n = blockIdx.x * 128 + wave * 32 + m;

    // A frags: [W0|W1] 32x64 bf16
    bf16x8 afrag[4];
#pragma unroll
    for (int q = 0; q < 4; ++q) {
        int kbase = q * 16 + hw * 8;
        bf16x8 fr;
#pragma unroll
        for (int j = 0; j < 8; ++j) {
            int k = kbase + j;
            int tap = k >> 5, c = k & 31;
            fr[j] = f2bf(w[(m * 32 + c) * 2 + tap]);
        }
        afrag[q] = fr;
    }
    // B frags: stacked h taps (rows k<32: h[t-d][c=k]; k>=32: h[t][c=k-32])
    bf16x8 bfrag[4];
#pragma unroll
    for (int q = 0; q < 4; ++q) {
        int kbase = q * 16 + hw * 8;
        int tap = kbase >> 5, c0 = kbase & 31;
        int tc = tap ? t : (t - d);
        const short* hb = h + (((size_t)((b * 32 + c0) * 13 + tc)) << 10) + n;
        bf16x8 fr;
#pragma unroll
        for (int j = 0; j < 8; ++j) fr[j] = hb[(size_t)j * 13 * 1024];
        bfrag[q] = fr;
    }
    f32x16 conv = {};
#pragma unroll
    for (int q = 0; q < 4; ++q)
        conv = __builtin_amdgcn_mfma_f32_32x32x16_bf16(afrag[q], bfrag[q], conv, 0, 0, 0);

    float gv[16];
#pragma unroll
    for (int r = 0; r < 16; ++r) {
        int o0 = (r & 3) + 8 * (r >> 2);
        float bv = hw ? bias[o0 + 4] : bias[o0];
        float a = conv[r] + bv;
        a = fminf(fmaxf(a, -25.f), 25.f);
        float e = __expf(-a), e2 = e * e;
        gv[r] = (1.f - e2) / ((1.f + e2) * (1.f + e));  // tanh(a)*sigmoid(a)
    }
    if (tt == Lt - 1) {  // t == 12: stash gated output for the skip GEMM
        short* gp = g12 + (((size_t)((b << 10) + n)) << 8) + li * 32;
#pragma unroll
        for (int r = 0; r < 16; ++r) {
            int o = (r & 3) + 8 * (r >> 2) + 4 * hw;
            gp[o] = f2bf(gv[r]);
        }
    }
    // relayout gv (C/D) -> B-operand frags for the mix GEMM
    unsigned pr[8], sp[8];
#pragma unroll
    for (int i = 0; i < 8; ++i) {
        pr[i] = pack2bf(gv[2 * i], gv[2 * i + 1]);
        sp[i] = (unsigned)__shfl_xor((int)pr[i], 32);
    }
    bf16x8 mfrag[2];
#pragma unroll
    for (int q = 0; q < 2; ++q) {
        union { unsigned u[4]; bf16x8 v; } tmpu;
        tmpu.u[0] = hw ? sp[q * 4 + 2] : pr[q * 4 + 0];
        tmpu.u[1] = hw ? sp[q * 4 + 3] : pr[q * 4 + 1];
        tmpu.u[2] = hw ? pr[q * 4 + 2] : sp[q * 4 + 0];
        tmpu.u[3] = hw ? pr[q * 4 + 3] : sp[q * 4 + 1];
        mfrag[q] = tmpu.v;
    }
    bf16x8 gwfrag[2];
#pragma unroll
    for (int q = 0; q < 2; ++q) {
        int kbase = q * 16 + hw * 8;
        bf16x8 fr;
#pragma unroll
        for (int j = 0; j < 8; ++j) fr[j] = f2bf(gcnw[m * 32 + kbase + j]);
        gwfrag[q] = fr;
    }
    f32x16 mix = {};
    mix = __builtin_amdgcn_mfma_f32_32x32x16_bf16(gwfrag[0], mfrag[0], mix, 0, 0, 0);
    mix = __builtin_amdgcn_mfma_f32_32x32x16_bf16(gwfrag[1], mfrag[1], mix, 0, 0, 0);
#pragma unroll
    for (int r = 0; r < 16; ++r) {
        int o2 = (r & 3) + 8 * (r >> 2) + 4 * hw;
        gm[(((size_t)((b * 32 + o2) * Lt + tt)) << 10) + n] = f2bf(mix[r]);
    }
}

// ======== shared 64x128 MFMA tile helper (BK=64, xor-swizzled LDS) ==========
template <int KLEN>
static __device__ __forceinline__ void mfma_tile(
        const short* __restrict__ Abase, int strideA,
        const short* __restrict__ Bbase, int strideB,
        short* As, short* Bs, int tid, f32x4 acc[2][4]) {
    int wave = tid >> 6, lane = tid & 63;
    const short* srcA[2]; short* dstA[2];
    const short* srcB[4]; short* dstB[4];
#pragma unroll
    for (int j = 0; j < 2; ++j) {
        int slot = j * 256 + wave * 64 + lane;
        int row = slot >> 3, pp = slot & 7;
        int col = (pp ^ ((row >> 1) & 7)) * 8;
        srcA[j] = Abase + (size_t)row * strideA + col;
        dstA[j] = As + slot * 8;
    }
#pragma unroll
    for (int j = 0; j < 4; ++j) {
        int slot = j * 256 + wave * 64 + lane;
        int row = slot >> 3, pp = slot & 7;
        int col = (pp ^ ((row >> 1) & 7)) * 8;
        srcB[j] = Bbase + (size_t)row * strideB + col;
        dstB[j] = Bs + slot * 8;
    }
    int wm = (wave & 1) * 32, wn = (wave >> 1) * 64;
    int quad = lane >> 4, lrow = lane & 15;
    const short* paw = As + (wm + lrow) * 64;
    const short* pbw = Bs + (wn + lrow) * 64;
    int off0 = ((quad) ^ ((lrow >> 1) & 7)) * 8;
    int off1 = ((4 + quad) ^ ((lrow >> 1) & 7)) * 8;
#pragma unroll 1
    for (int kk = 0; kk < KLEN; kk += 64) {
#pragma unroll
        for (int j = 0; j < 2; ++j) GLOAD16(srcA[j] + kk, dstA[j]);
#pragma unroll
        for (int j = 0; j < 4; ++j) GLOAD16(srcB[j] + kk, dstB[j]);
        __syncthreads();
#pragma unroll
        for (int ks = 0; ks < 2; ++ks) {
            int off = ks ? off1 : off0;
            bf16x8 a[2], b[4];
#pragma unroll
            for (int i = 0; i < 2; ++i) a[i] = *(const bf16x8*)(paw + i * 16 * 64 + off);
#pragma unroll
            for (int i = 0; i < 4; ++i) b[i] = *(const bf16x8*)(pbw + i * 16 * 64 + off);
#pragma unroll
            for (int mi = 0; mi < 2; ++mi)
#pragma unroll
                for (int ni = 0; ni < 4; ++ni)
                    acc[mi][ni] = __builtin_amdgcn_mfma_f32_16x16x32_bf16(a[mi], b[ni], acc[mi][ni], 0, 0, 0);
        }
        __syncthreads();
    }
}

// ---------------- diffusion MFMA + fused gcn epilogue (64x128) ---------------
__global__ __launch_bounds__(256) void diff_fused(const short* __restrict__ gm,
                                                  const short* __restrict__ adpT,
                                                  short* __restrict__ h,
                                                  const float* __restrict__ gb,
                                                  const float* __restrict__ bng,
                                                  const float* __restrict__ bnb,
                                                  const float* __restrict__ bnm,
                                                  const float* __restrict__ bnv,
                                                  int t0, int Lt) {
    __shared__ __align__(16) short As[64 * 64];
    __shared__ __align__(16) short Bs[128 * 64];
    __shared__ float sgb[32], sinv[32], smean[32], sbeta[32];
    int tid = threadIdx.x;
    int n0 = blockIdx.x * 128;
    int m0 = blockIdx.y * 64;
    if (tid < 32) {
        sgb[tid] = gb[tid];
        sinv[tid] = bng[tid] * rsqrtf(bnv[tid] + 1e-5f);
        smean[tid] = bnm[tid];
        sbeta[tid] = bnb[tid];
    }
    f32x4 acc[2][4] = {};
    mfma_tile<1024>(gm + ((size_t)m0 << 10), 1024,
                    adpT + ((size_t)n0 << 10), 1024, As, Bs, tid, acc);
    int wave = tid >> 6, lane = tid & 63;
    int wm = (wave & 1) * 32, wn = (wave >> 1) * 64;
    int quad = lane >> 4, lrow = lane & 15;
#pragma unroll
    for (int mi = 0; mi < 2; ++mi) {
#pragma unroll
        for (int r = 0; r < 4; ++r) {
            int m = m0 + wm + mi * 16 + quad * 4 + r;
            unsigned bc = (unsigned)m / (unsigned)Lt;
            int tt = m - (int)bc * Lt;
            int c = bc & 31;
            float invv = sinv[c], meanv = smean[c], betav = sbeta[c], gbv = sgb[c];
            short* crow = h + (((size_t)(bc * LLEN + t0 + tt)) << 10) + n0 + wn + lrow;
#pragma unroll
            for (int ni = 0; ni < 4; ++ni) {
                float v = fmaxf(acc[mi][ni][r] + gbv, 0.f) + bf2f(crow[ni * 16]);
                crow[ni * 16] = f2bf((v - meanv) * invv + betav);
            }
        }
    }
}

// ---------------- skip GEMM (64x128): skipT = relu(Wcat @ g12 + sbcat) ------
__global__ __launch_bounds__(256) void skip_mfma(const short* __restrict__ g12,
                                                 const short* __restrict__ wcat,
                                                 const float* __restrict__ sbcat,
                                                 short* __restrict__ skipT) {
    __shared__ __align__(16) short As[64 * 64];
    __shared__ __align__(16) short Bs[128 * 64];
    int tid = threadIdx.x;
    int s0 = blockIdx.x * 128;
    int m0 = blockIdx.y * 64;
    int b = blockIdx.z;
    f32x4 acc[2][4] = {};
    mfma_tile<256>(g12 + (((size_t)((b << 10) + m0)) << 8), 256,
                   wcat + ((size_t)s0 << 8), 256, As, Bs, tid, acc);
    int wave = tid >> 6, lane = tid & 63;
    int wm = (wave & 1) * 32, wn = (wave >> 1) * 64;
    int quad = lane >> 4, lrow = lane & 15;
#pragma unroll
    for (int mi = 0; mi < 2; ++mi) {
#pragma unroll
        for (int r = 0; r < 4; ++r) {
            int m = m0 + wm + mi * 16 + quad * 4 + r;
            short* crow = skipT + (((size_t)((b << 10) + m)) << 8) + s0 + wn + lrow;
#pragma unroll
            for (int ni = 0; ni < 4; ++ni) {
                int col = s0 + wn + lrow + ni * 16;
                crow[ni * 16] = f2bf(fmaxf(acc[mi][ni][r] + sbcat[col], 0.f));
            }
        }
    }
}

// ---------------- end1 (64x128): y1 = relu(e1w @ skipT + e1b) ----------------
__global__ __launch_bounds__(256) void end1_mfma(const short* __restrict__ skipT,
                                                 const short* __restrict__ e1wb,
                                                 const float* __restrict__ e1b,
                                                 short* __restrict__ y1) {
    __shared__ __align__(16) short As[64 * 64];
    __shared__ __align__(16) short Bs[128 * 64];
    int tid = threadIdx.x;
    int n0 = blockIdx.x * 128;
    int e0 = blockIdx.y * 64;
    int b = blockIdx.z;
    f32x4 acc[2][4] = {};
    mfma_tile<256>(e1wb + ((size_t)e0 << 8), 256,
                   skipT + (((size_t)((b << 10) + n0)) << 8), 256, As, Bs, tid, acc);
    int wave = tid >> 6, lane = tid & 63;
    int wm = (wave & 1) * 32, wn = (wave >> 1) * 64;
    int quad = lane >> 4, lrow = lane & 15;
#pragma unroll
    for (int mi = 0; mi < 2; ++mi) {
#pragma unroll
        for (int r = 0; r < 4; ++r) {
            int e = e0 + wm + mi * 16 + quad * 4 + r;
            float bv = e1b[e];
            short* crow = y1 + (((size_t)(b * 512 + e)) << 10) + n0 + wn + lrow;
#pragma unroll
            for (int ni = 0; ni < 4; ++ni)
                crow[ni * 16] = f2bf(fmaxf(acc[mi][ni][r] + bv, 0.f));
        }
    }
}

// ---------------- end2: out[b,n,o] = W2 @ y1 + b2 (parallel e-split) --------
__global__ __launch_bounds__(256) void end2_kernel(const short* __restrict__ y1,
                                                   const float* __restrict__ w2,
                                                   const float* __restrict__ b2,
                                                   float* __restrict__ out) {
    __shared__ float sw[12][512];
    __shared__ float ps[4][12][128];
    int tid = threadIdx.x;
    for (int idx = tid; idx < 6144; idx += 256) sw[idx >> 9][idx & 511] = w2[idx];
    __syncthreads();
    int n0 = blockIdx.x * 128;
    int bb = blockIdx.y;
    int nl = (tid & 63) * 2;
    int ec = tid >> 6;
    float acc0[12], acc1[12];
#pragma unroll
    for (int o = 0; o < 12; ++o) { acc0[o] = 0.f; acc1[o] = 0.f; }
    const short* yb = y1 + (((size_t)(bb * 512 + ec * 128)) << 10) + n0 + nl;
    for (int e = 0; e < 128; ++e) {
        ushort2 yv = *(const ushort2*)(yb + ((size_t)e << 10));
        float v0 = bf2f((short)yv.x), v1 = bf2f((short)yv.y);
        const float* we = &sw[0][ec * 128 + e];
#pragma unroll
        for (int o = 0; o < 12; ++o) {
            float wv = we[o * 512];
            acc0[o] += wv * v0;
            acc1[o] += wv * v1;
        }
    }
#pragma unroll
    for (int o = 0; o < 12; ++o) {
        ps[ec][o][nl] = acc0[o];
        ps[ec][o][nl + 1] = acc1[o];
    }
    __syncthreads();
    for (int idx = tid; idx < 1536; idx += 256) {
        int o = idx >> 7, nn = idx & 127;
        float s = b2[o] + ps[0][o][nn] + ps[1][o][nn] + ps[2][o][nn] + ps[3][o][nn];
        out[((size_t)(bb * NNODE + nn + n0)) * 12 + o] = s;
    }
}

extern "C" void kernel_launch(void* const* d_in, const int* in_sizes, int n_in,
                              void* d_out, int out_size, void* d_ws, size_t ws_size,
                              hipStream_t stream) {
    const float* x       = (const float*)d_in[0];
    const float* emb     = (const float*)d_in[1];
    const float* start_w = (const float*)d_in[2];
    const float* start_b = (const float*)d_in[3];
    const float* tcn_w   = (const float*)d_in[4];
    const float* tcn_b   = (const float*)d_in[5];
    const float* skip_w  = (const float*)d_in[6];
    const float* skip_b  = (const float*)d_in[7];
    const float* gcn_w   = (const float*)d_in[8];
    const float* gcn_b   = (const float*)d_in[9];
    const float* bn_g    = (const float*)d_in[10];
    const float* bn_b    = (const float*)d_in[11];
    const float* bn_m    = (const float*)d_in[12];
    const float* bn_v    = (const float*)d_in[13];
    const float* e1w     = (const float*)d_in[14];
    const float* e1b     = (const float*)d_in[15];
    const float* e2w     = (const float*)d_in[16];
    const float* e2b     = (const float*)d_in[17];
    float* out = (float*)d_out;

    char* wsb = (char*)d_ws;
    short* adpT  = (short*)(wsb);                    // 2,097,152
    float* mx    = (float*)(wsb + 2097152u);         // 4,096
    float* inv   = (float*)(wsb + 2101248u);         // 4,096
    short* h     = (short*)(wsb + 2105344u);         // 13,631,488 (bf16)
    short* gm    = (short*)(wsb + 15736832u);        // 12,582,912 (max Lt=12)
    short* g12   = (short*)(wsb + 28319744u);        // 8,388,608
    short* wcat  = (short*)(wsb + 36708352u);        // 131,072
    float* sbcat = (float*)(wsb + 36839424u);        // 1,024
    short* e1wb  = (short*)(wsb + 36840448u);        // 262,144
    short* skipT = (short*)(wsb + 37102592u);        // 8,388,608
    short* y1    = (short*)(wsb + 45491200u);        // 16,777,216

    prep_kernel<<<dim3(2624), dim3(256), 0, stream>>>(
        emb, x, start_w, start_b, skip_w, skip_b, e1w,
        mx, inv, h, wcat, sbcat, e1wb);
    adpT_kernel<<<dim3(1024), dim3(256), 0, stream>>>(emb, mx, inv, adpT);

    const int dil[8] = {1, 2, 1, 2, 1, 2, 1, 2};
    const int t0s[8] = {1, 3, 4, 6, 7, 9, 10, 12};
    for (int i = 0; i < 8; ++i) {
        int d = dil[i];
        int t0 = t0s[i];
        int Lt = 13 - t0;
        tcn_mfma<<<dim3(8, Lt, 16), dim3(256), 0, stream>>>(
            h, gm, g12, tcn_w + i * 2048, tcn_b + i * 32, gcn_w + i * 1024,
            d, t0, Lt, i);
        diff_fused<<<dim3(8, 8 * Lt), dim3(256), 0, stream>>>(
            gm, adpT, h, gcn_b + i * 32,
            bn_g + i * 32, bn_b + i * 32, bn_m + i * 32, bn_v + i * 32, t0, Lt);
    }

    skip_mfma<<<dim3(2, 16, 16), dim3(256), 0, stream>>>(g12, wcat, sbcat, skipT);
    end1_mfma<<<dim3(8, 8, 16), dim3(256), 0, stream>>>(skipT, e1wb, e1b, y1);
    end2_kernel<<<dim3(8, 16), dim3(256), 0, stream>>>(y1, e2w, e2b, out);
}

// Round 11
// 392.199 us; speedup vs baseline: 1.0260x; 1.0260x over previous
//
#include <hip/hip_runtime.h>
#include <math.h>

// GraphWaveNet forward, MI355X. Round 11:
//  - revert h to fp32 (R10 bf16-h regressed: h is L2/L3-resident, conversions
//    cost more than the saved HBM traffic)
//  - DROP layer-7 diffusion entirely (h_8 is dead: output head uses skip only)
//  - diff MFMA switched to 32x32x16 (15% faster rate, 2x FLOP per barrier;
//    lane mappings verified by R9's passing tcn kernel)
//   h    : [B=16, C=32, t=13, N=1024] fp32 ; gm : [m][N] bf16
//   g12  : [b][n][256] bf16 ; adpT : [w][v] bf16
//   skipT: [b][n][s=256] bf16 ; y1 : [b][e=512][n] bf16 ; out [B,N,O] fp32

#define NBATCH 16
#define LLEN 13
#define NNODE 1024

typedef __attribute__((ext_vector_type(8))) short bf16x8;
typedef __attribute__((ext_vector_type(4))) float f32x4;
typedef __attribute__((ext_vector_type(16))) float f32x16;

#define GLOAD16(gp, lp) __builtin_amdgcn_global_load_lds( \
    (const __attribute__((address_space(1))) void*)(gp), \
    (__attribute__((address_space(3))) void*)(lp), 16, 0, 0)

static __device__ inline short f2bf(float x) {
    union { float f; unsigned u; } v; v.f = x;
    unsigned r = v.u + 0x7FFFu + ((v.u >> 16) & 1u);
    return (short)(r >> 16);
}
static __device__ inline float bf2f(short x) {
    union { unsigned u; float f; } v; v.u = ((unsigned)(unsigned short)x) << 16;
    return v.f;
}
static __device__ inline unsigned pack2bf(float lo, float hi) {
    return (unsigned)(unsigned short)f2bf(lo) | ((unsigned)(unsigned short)f2bf(hi) << 16);
}

// ---------------- prep: adp stats | start conv | weight repack ---------------
__global__ __launch_bounds__(256) void prep_kernel(
        const float* __restrict__ emb, const float* __restrict__ x,
        const float* __restrict__ start_w, const float* __restrict__ start_b,
        const float* __restrict__ skip_w, const float* __restrict__ skip_b,
        const float* __restrict__ e1w,
        float* __restrict__ mx, float* __restrict__ inv, float* __restrict__ h,
        short* __restrict__ wcat, float* __restrict__ sbcat, short* __restrict__ e1wb) {
    int bid = blockIdx.x;
    int tid = threadIdx.x;
    if (bid < 1024) {
        int v = bid;
        __shared__ float red[256];
        float ev[10];
#pragma unroll
        for (int k = 0; k < 10; ++k) ev[k] = emb[v * 10 + k];
        float sc[4];
#pragma unroll
        for (int j = 0; j < 4; ++j) {
            int w = tid + j * 256;
            float s = 0.f;
#pragma unroll
            for (int k = 0; k < 10; ++k) s += ev[k] * emb[w * 10 + k];
            sc[j] = fmaxf(s, 0.f);
        }
        float m = fmaxf(fmaxf(sc[0], sc[1]), fmaxf(sc[2], sc[3]));
        red[tid] = m;
        __syncthreads();
        for (int s = 128; s > 0; s >>= 1) {
            if (tid < s) red[tid] = fmaxf(red[tid], red[tid + s]);
            __syncthreads();
        }
        m = red[0];
        __syncthreads();
        float sum = 0.f;
#pragma unroll
        for (int j = 0; j < 4; ++j) sum += __expf(sc[j] - m);
        red[tid] = sum;
        __syncthreads();
        for (int s = 128; s > 0; s >>= 1) {
            if (tid < s) red[tid] += red[tid + s];
            __syncthreads();
        }
        if (tid == 0) { mx[v] = m; inv[v] = 1.f / red[0]; }
    } else if (bid < 1856) {
        int it = (bid - 1024) * 256 + tid;
        int n = it & 1023, rest = it >> 10;
        int t = rest % 13, b = rest / 13;
        float2 xv = *(const float2*)(x + (size_t)it * 2);
#pragma unroll
        for (int r = 0; r < 32; ++r)
            h[((b * 32 + r) * 13 + t) * 1024 + n] =
                start_w[r * 2] * xv.x + start_w[r * 2 + 1] * xv.y + start_b[r];
    } else {
        int idx = (bid - 1856) * 256 + tid;
        if (idx < 65536) {
            int s = idx >> 8, k = idx & 255, i = k >> 5, c = k & 31;
            wcat[idx] = f2bf(skip_w[(i * 256 + s) * 32 + c]);
        } else {
            int j = idx - 65536;
            e1wb[j] = f2bf(e1w[j]);
        }
        if (idx < 256) {
            float s = 0.f;
#pragma unroll
            for (int i = 0; i < 8; ++i) s += skip_b[i * 256 + idx];
            sbcat[idx] = s;
        }
    }
}

// ---------------- adpT[w][v] = softmax_v(relu(E E^T))[v][w] bf16 ------------
__global__ void adpT_kernel(const float* __restrict__ emb, const float* __restrict__ mx,
                            const float* __restrict__ inv, short* __restrict__ adpT) {
    int w = blockIdx.x;
    int tid = threadIdx.x;
    __shared__ float ew[10];
    if (tid < 10) ew[tid] = emb[w * 10 + tid];
    __syncthreads();
#pragma unroll
    for (int j = 0; j < 4; ++j) {
        int v = tid + j * 256;
        float s = 0.f;
#pragma unroll
        for (int k = 0; k < 10; ++k) s += ew[k] * emb[v * 10 + k];
        s = fmaxf(s, 0.f);
        adpT[w * 1024 + v] = f2bf(__expf(s - mx[v]) * inv[v]);
    }
}

// ---------------- TCN as MFMA: conv+gate(+mix) -> gm bf16 --------------------
__global__ __launch_bounds__(256) void tcn_mfma(
        const float* __restrict__ h, short* __restrict__ gm,
        short* __restrict__ g12,
        const float* __restrict__ w, const float* __restrict__ bias,
        const float* __restrict__ gcnw,
        int d, int t0, int Lt, int li, int do_mix) {
    int tid = threadIdx.x;
    int wave = tid >> 6, lane = tid & 63;
    int m = lane & 31, hw = lane >> 5;
    int tt = blockIdx.y, t = t0 + tt, b = blockIdx.z;
    int n = blockIdx.x * 128 + wave * 32 + m;

    bf16x8 afrag[4];
#pragma unroll
    for (int q = 0; q < 4; ++q) {
        int kbase = q * 16 + hw * 8;
        bf16x8 fr;
#pragma unroll
        for (int j = 0; j < 8; ++j) {
            int k = kbase + j;
            int tap = k >> 5, c = k & 31;
            fr[j] = f2bf(w[(m * 32 + c) * 2 + tap]);
        }
        afrag[q] = fr;
    }
    bf16x8 bfrag[4];
#pragma unroll
    for (int q = 0; q < 4; ++q) {
        int kbase = q * 16 + hw * 8;
        int tap = kbase >> 5, c0 = kbase & 31;
        int tc = tap ? t : (t - d);
        const float* hb = h + (((size_t)((b * 32 + c0) * 13 + tc)) << 10) + n;
        bf16x8 fr;
#pragma unroll
        for (int j = 0; j < 8; ++j) fr[j] = f2bf(hb[(size_t)j * 13 * 1024]);
        bfrag[q] = fr;
    }
    f32x16 conv = {};
#pragma unroll
    for (int q = 0; q < 4; ++q)
        conv = __builtin_amdgcn_mfma_f32_32x32x16_bf16(afrag[q], bfrag[q], conv, 0, 0, 0);

    float gv[16];
#pragma unroll
    for (int r = 0; r < 16; ++r) {
        int o0 = (r & 3) + 8 * (r >> 2);
        float bv = hw ? bias[o0 + 4] : bias[o0];
        float a = conv[r] + bv;
        a = fminf(fmaxf(a, -25.f), 25.f);
        float e = __expf(-a), e2 = e * e;
        gv[r] = (1.f - e2) / ((1.f + e2) * (1.f + e));  // tanh(a)*sigmoid(a)
    }
    if (tt == Lt - 1) {  // t == 12: stash gated output for the skip GEMM
        short* gp = g12 + (((size_t)((b << 10) + n)) << 8) + li * 32;
#pragma unroll
        for (int r = 0; r < 16; ++r) {
            int o = (r & 3) + 8 * (r >> 2) + 4 * hw;
            gp[o] = f2bf(gv[r]);
        }
    }
    if (!do_mix) return;   // layer 7: gm/diffusion output is dead code

    unsigned pr[8], sp[8];
#pragma unroll
    for (int i = 0; i < 8; ++i) {
        pr[i] = pack2bf(gv[2 * i], gv[2 * i + 1]);
        sp[i] = (unsigned)__shfl_xor((int)pr[i], 32);
    }
    bf16x8 mfrag[2];
#pragma unroll
    for (int q = 0; q < 2; ++q) {
        union { unsigned u[4]; bf16x8 v; } tmpu;
        tmpu.u[0] = hw ? sp[q * 4 + 2] : pr[q * 4 + 0];
        tmpu.u[1] = hw ? sp[q * 4 + 3] : pr[q * 4 + 1];
        tmpu.u[2] = hw ? pr[q * 4 + 2] : sp[q * 4 + 0];
        tmpu.u[3] = hw ? pr[q * 4 + 3] : sp[q * 4 + 1];
        mfrag[q] = tmpu.v;
    }
    bf16x8 gwfrag[2];
#pragma unroll
    for (int q = 0; q < 2; ++q) {
        int kbase = q * 16 + hw * 8;
        bf16x8 fr;
#pragma unroll
        for (int j = 0; j < 8; ++j) fr[j] = f2bf(gcnw[m * 32 + kbase + j]);
        gwfrag[q] = fr;
    }
    f32x16 mix = {};
    mix = __builtin_amdgcn_mfma_f32_32x32x16_bf16(gwfrag[0], mfrag[0], mix, 0, 0, 0);
    mix = __builtin_amdgcn_mfma_f32_32x32x16_bf16(gwfrag[1], mfrag[1], mix, 0, 0, 0);
#pragma unroll
    for (int r = 0; r < 16; ++r) {
        int o2 = (r & 3) + 8 * (r >> 2) + 4 * hw;
        gm[(((size_t)((b * 32 + o2) * Lt + tt)) << 10) + n] = f2bf(mix[r]);
    }
}

// ======== 64x128 MFMA tile, 32x32x16 path (diff) ============================
template <int KLEN>
static __device__ __forceinline__ void mfma_tile32(
        const short* __restrict__ Abase, int strideA,
        const short* __restrict__ Bbase, int strideB,
        short* As, short* Bs, int tid, f32x16 acc[2]) {
    int wave = tid >> 6, lane = tid & 63;
    const short* srcA[2]; short* dstA[2];
    const short* srcB[4]; short* dstB[4];
#pragma unroll
    for (int j = 0; j < 2; ++j) {
        int slot = j * 256 + wave * 64 + lane;
        int row = slot >> 3, pp = slot & 7;
        int col = (pp ^ ((row >> 1) & 7)) * 8;
        srcA[j] = Abase + (size_t)row * strideA + col;
        dstA[j] = As + slot * 8;
    }
#pragma unroll
    for (int j = 0; j < 4; ++j) {
        int slot = j * 256 + wave * 64 + lane;
        int row = slot >> 3, pp = slot & 7;
        int col = (pp ^ ((row >> 1) & 7)) * 8;
        srcB[j] = Bbase + (size_t)row * strideB + col;
        dstB[j] = Bs + slot * 8;
    }
    int wm = (wave & 1) * 32, wn = (wave >> 1) * 64;
    int m32 = lane & 31, hw = lane >> 5;
    const short* paw = As + (wm + m32) * 64;
    int aswz = ((wm + m32) >> 1) & 7;
    const short* pb0 = Bs + (wn + m32) * 64;
    int bswz0 = ((wn + m32) >> 1) & 7;
    const short* pb1 = Bs + (wn + 32 + m32) * 64;
    int bswz1 = ((wn + 32 + m32) >> 1) & 7;
#pragma unroll 1
    for (int kk = 0; kk < KLEN; kk += 64) {
#pragma unroll
        for (int j = 0; j < 2; ++j) GLOAD16(srcA[j] + kk, dstA[j]);
#pragma unroll
        for (int j = 0; j < 4; ++j) GLOAD16(srcB[j] + kk, dstB[j]);
        __syncthreads();
#pragma unroll
        for (int ks = 0; ks < 4; ++ks) {
            int p = ks * 2 + hw;
            bf16x8 a = *(const bf16x8*)(paw + ((p ^ aswz) << 3));
            bf16x8 b0v = *(const bf16x8*)(pb0 + ((p ^ bswz0) << 3));
            bf16x8 b1v = *(const bf16x8*)(pb1 + ((p ^ bswz1) << 3));
            acc[0] = __builtin_amdgcn_mfma_f32_32x32x16_bf16(a, b0v, acc[0], 0, 0, 0);
            acc[1] = __builtin_amdgcn_mfma_f32_32x32x16_bf16(a, b1v, acc[1], 0, 0, 0);
        }
        __syncthreads();
    }
}

// ======== 64x128 MFMA tile, 16x16x32 path (skip/end1, proven) ===============
template <int KLEN>
static __device__ __forceinline__ void mfma_tile(
        const short* __restrict__ Abase, int strideA,
        const short* __restrict__ Bbase, int strideB,
        short* As, short* Bs, int tid, f32x4 acc[2][4]) {
    int wave = tid >> 6, lane = tid & 63;
    const short* srcA[2]; short* dstA[2];
    const short* srcB[4]; short* dstB[4];
#pragma unroll
    for (int j = 0; j < 2; ++j) {
        int slot = j * 256 + wave * 64 + lane;
        int row = slot >> 3, pp = slot & 7;
        int col = (pp ^ ((row >> 1) & 7)) * 8;
        srcA[j] = Abase + (size_t)row * strideA + col;
        dstA[j] = As + slot * 8;
    }
#pragma unroll
    for (int j = 0; j < 4; ++j) {
        int slot = j * 256 + wave * 64 + lane;
        int row = slot >> 3, pp = slot & 7;
        int col = (pp ^ ((row >> 1) & 7)) * 8;
        srcB[j] = Bbase + (size_t)row * strideB + col;
        dstB[j] = Bs + slot * 8;
    }
    int wm = (wave & 1) * 32, wn = (wave >> 1) * 64;
    int quad = lane >> 4, lrow = lane & 15;
    const short* paw = As + (wm + lrow) * 64;
    const short* pbw = Bs + (wn + lrow) * 64;
    int off0 = ((quad) ^ ((lrow >> 1) & 7)) * 8;
    int off1 = ((4 + quad) ^ ((lrow >> 1) & 7)) * 8;
#pragma unroll 1
    for (int kk = 0; kk < KLEN; kk += 64) {
#pragma unroll
        for (int j = 0; j < 2; ++j) GLOAD16(srcA[j] + kk, dstA[j]);
#pragma unroll
        for (int j = 0; j < 4; ++j) GLOAD16(srcB[j] + kk, dstB[j]);
        __syncthreads();
#pragma unroll
        for (int ks = 0; ks < 2; ++ks) {
            int off = ks ? off1 : off0;
            bf16x8 a[2], b[4];
#pragma unroll
            for (int i = 0; i < 2; ++i) a[i] = *(const bf16x8*)(paw + i * 16 * 64 + off);
#pragma unroll
            for (int i = 0; i < 4; ++i) b[i] = *(const bf16x8*)(pbw + i * 16 * 64 + off);
#pragma unroll
            for (int mi = 0; mi < 2; ++mi)
#pragma unroll
                for (int ni = 0; ni < 4; ++ni)
                    acc[mi][ni] = __builtin_amdgcn_mfma_f32_16x16x32_bf16(a[mi], b[ni], acc[mi][ni], 0, 0, 0);
        }
        __syncthreads();
    }
}

// ---------------- diffusion MFMA (32x32x16) + fused gcn epilogue -------------
__global__ __launch_bounds__(256) void diff_fused(const short* __restrict__ gm,
                                                  const short* __restrict__ adpT,
                                                  float* __restrict__ h,
                                                  const float* __restrict__ gb,
                                                  const float* __restrict__ bng,
                                                  const float* __restrict__ bnb,
                                                  const float* __restrict__ bnm,
                                                  const float* __restrict__ bnv,
                                                  int t0, int Lt) {
    __shared__ __align__(16) short As[64 * 64];
    __shared__ __align__(16) short Bs[128 * 64];
    __shared__ float sgb[32], sinv[32], smean[32], sbeta[32];
    int tid = threadIdx.x;
    int n0 = blockIdx.x * 128;
    int m0 = blockIdx.y * 64;
    if (tid < 32) {
        sgb[tid] = gb[tid];
        sinv[tid] = bng[tid] * rsqrtf(bnv[tid] + 1e-5f);
        smean[tid] = bnm[tid];
        sbeta[tid] = bnb[tid];
    }
    f32x16 acc[2] = {};
    mfma_tile32<1024>(gm + ((size_t)m0 << 10), 1024,
                      adpT + ((size_t)n0 << 10), 1024, As, Bs, tid, acc);
    int wave = tid >> 6, lane = tid & 63;
    int wm = (wave & 1) * 32, wn = (wave >> 1) * 64;
    int m32 = lane & 31, hw = lane >> 5;
#pragma unroll
    for (int nh = 0; nh < 2; ++nh) {
#pragma unroll
        for (int r = 0; r < 16; ++r) {
            int m = m0 + wm + (r & 3) + 8 * (r >> 2) + 4 * hw;
            unsigned bc = (unsigned)m / (unsigned)Lt;
            int tt = m - (int)bc * Lt;
            int c = bc & 31;
            float* crow = h + (((size_t)(bc * LLEN + t0 + tt)) << 10) + n0 + wn + nh * 32 + m32;
            float v = fmaxf(acc[nh][r] + sgb[c], 0.f) + *crow;
            *crow = (v - smean[c]) * sinv[c] + sbeta[c];
        }
    }
}

// ---------------- skip GEMM (64x128): skipT = relu(Wcat @ g12 + sbcat) ------
__global__ __launch_bounds__(256) void skip_mfma(const short* __restrict__ g12,
                                                 const short* __restrict__ wcat,
                                                 const float* __restrict__ sbcat,
                                                 short* __restrict__ skipT) {
    __shared__ __align__(16) short As[64 * 64];
    __shared__ __align__(16) short Bs[128 * 64];
    int tid = threadIdx.x;
    int s0 = blockIdx.x * 128;
    int m0 = blockIdx.y * 64;
    int b = blockIdx.z;
    f32x4 acc[2][4] = {};
    mfma_tile<256>(g12 + (((size_t)((b << 10) + m0)) << 8), 256,
                   wcat + ((size_t)s0 << 8), 256, As, Bs, tid, acc);
    int wave = tid >> 6, lane = tid & 63;
    int wm = (wave & 1) * 32, wn = (wave >> 1) * 64;
    int quad = lane >> 4, lrow = lane & 15;
#pragma unroll
    for (int mi = 0; mi < 2; ++mi) {
#pragma unroll
        for (int r = 0; r < 4; ++r) {
            int m = m0 + wm + mi * 16 + quad * 4 + r;
            short* crow = skipT + (((size_t)((b << 10) + m)) << 8) + s0 + wn + lrow;
#pragma unroll
            for (int ni = 0; ni < 4; ++ni) {
                int col = s0 + wn + lrow + ni * 16;
                crow[ni * 16] = f2bf(fmaxf(acc[mi][ni][r] + sbcat[col], 0.f));
            }
        }
    }
}

// ---------------- end1 (64x128): y1 = relu(e1w @ skipT + e1b) ----------------
__global__ __launch_bounds__(256) void end1_mfma(const short* __restrict__ skipT,
                                                 const short* __restrict__ e1wb,
                                                 const float* __restrict__ e1b,
                                                 short* __restrict__ y1) {
    __shared__ __align__(16) short As[64 * 64];
    __shared__ __align__(16) short Bs[128 * 64];
    int tid = threadIdx.x;
    int n0 = blockIdx.x * 128;
    int e0 = blockIdx.y * 64;
    int b = blockIdx.z;
    f32x4 acc[2][4] = {};
    mfma_tile<256>(e1wb + ((size_t)e0 << 8), 256,
                   skipT + (((size_t)((b << 10) + n0)) << 8), 256, As, Bs, tid, acc);
    int wave = tid >> 6, lane = tid & 63;
    int wm = (wave & 1) * 32, wn = (wave >> 1) * 64;
    int quad = lane >> 4, lrow = lane & 15;
#pragma unroll
    for (int mi = 0; mi < 2; ++mi) {
#pragma unroll
        for (int r = 0; r < 4; ++r) {
            int e = e0 + wm + mi * 16 + quad * 4 + r;
            float bv = e1b[e];
            short* crow = y1 + (((size_t)(b * 512 + e)) << 10) + n0 + wn + lrow;
#pragma unroll
            for (int ni = 0; ni < 4; ++ni)
                crow[ni * 16] = f2bf(fmaxf(acc[mi][ni][r] + bv, 0.f));
        }
    }
}

// ---------------- end2: out[b,n,o] = W2 @ y1 + b2 (parallel e-split) --------
__global__ __launch_bounds__(256) void end2_kernel(const short* __restrict__ y1,
                                                   const float* __restrict__ w2,
                                                   const float* __restrict__ b2,
                                                   float* __restrict__ out) {
    __shared__ float sw[12][512];
    __shared__ float ps[4][12][128];
    int tid = threadIdx.x;
    for (int idx = tid; idx < 6144; idx += 256) sw[idx >> 9][idx & 511] = w2[idx];
    __syncthreads();
    int n0 = blockIdx.x * 128;
    int bb = blockIdx.y;
    int nl = (tid & 63) * 2;
    int ec = tid >> 6;
    float acc0[12], acc1[12];
#pragma unroll
    for (int o = 0; o < 12; ++o) { acc0[o] = 0.f; acc1[o] = 0.f; }
    const short* yb = y1 + (((size_t)(bb * 512 + ec * 128)) << 10) + n0 + nl;
    for (int e = 0; e < 128; ++e) {
        ushort2 yv = *(const ushort2*)(yb + ((size_t)e << 10));
        float v0 = bf2f((short)yv.x), v1 = bf2f((short)yv.y);
        const float* we = &sw[0][ec * 128 + e];
#pragma unroll
        for (int o = 0; o < 12; ++o) {
            float wv = we[o * 512];
            acc0[o] += wv * v0;
            acc1[o] += wv * v1;
        }
    }
#pragma unroll
    for (int o = 0; o < 12; ++o) {
        ps[ec][o][nl] = acc0[o];
        ps[ec][o][nl + 1] = acc1[o];
    }
    __syncthreads();
    for (int idx = tid; idx < 1536; idx += 256) {
        int o = idx >> 7, nn = idx & 127;
        float s = b2[o] + ps[0][o][nn] + ps[1][o][nn] + ps[2][o][nn] + ps[3][o][nn];
        out[((size_t)(bb * NNODE + nn + n0)) * 12 + o] = s;
    }
}

extern "C" void kernel_launch(void* const* d_in, const int* in_sizes, int n_in,
                              void* d_out, int out_size, void* d_ws, size_t ws_size,
                              hipStream_t stream) {
    const float* x       = (const float*)d_in[0];
    const float* emb     = (const float*)d_in[1];
    const float* start_w = (const float*)d_in[2];
    const float* start_b = (const float*)d_in[3];
    const float* tcn_w   = (const float*)d_in[4];
    const float* tcn_b   = (const float*)d_in[5];
    const float* skip_w  = (const float*)d_in[6];
    const float* skip_b  = (const float*)d_in[7];
    const float* gcn_w   = (const float*)d_in[8];
    const float* gcn_b   = (const float*)d_in[9];
    const float* bn_g    = (const float*)d_in[10];
    const float* bn_b    = (const float*)d_in[11];
    const float* bn_m    = (const float*)d_in[12];
    const float* bn_v    = (const float*)d_in[13];
    const float* e1w     = (const float*)d_in[14];
    const float* e1b     = (const float*)d_in[15];
    const float* e2w     = (const float*)d_in[16];
    const float* e2b     = (const float*)d_in[17];
    float* out = (float*)d_out;

    char* wsb = (char*)d_ws;
    short* adpT  = (short*)(wsb);                    // 2,097,152
    float* mx    = (float*)(wsb + 2097152u);         // 4,096
    float* inv   = (float*)(wsb + 2101248u);         // 4,096
    float* h     = (float*)(wsb + 2105344u);         // 27,262,976
    short* gm    = (short*)(wsb + 29368320u);        // 12,582,912 (max Lt=12)
    short* g12   = (short*)(wsb + 41951232u);        // 8,388,608
    short* wcat  = (short*)(wsb + 50339840u);        // 131,072
    float* sbcat = (float*)(wsb + 50470912u);        // 1,024
    short* e1wb  = (short*)(wsb + 50471936u);        // 262,144
    short* skipT = (short*)(wsb + 50734080u);        // 8,388,608
    short* y1    = (short*)(wsb + 59122688u);        // 16,777,216

    prep_kernel<<<dim3(2624), dim3(256), 0, stream>>>(
        emb, x, start_w, start_b, skip_w, skip_b, e1w,
        mx, inv, h, wcat, sbcat, e1wb);
    adpT_kernel<<<dim3(1024), dim3(256), 0, stream>>>(emb, mx, inv, adpT);

    const int dil[8] = {1, 2, 1, 2, 1, 2, 1, 2};
    const int t0s[8] = {1, 3, 4, 6, 7, 9, 10, 12};
    for (int i = 0; i < 8; ++i) {
        int d = dil[i];
        int t0 = t0s[i];
        int Lt = 13 - t0;
        int do_mix = (i < 7) ? 1 : 0;
        tcn_mfma<<<dim3(8, Lt, 16), dim3(256), 0, stream>>>(
            h, gm, g12, tcn_w + i * 2048, tcn_b + i * 32, gcn_w + i * 1024,
            d, t0, Lt, i, do_mix);
        if (do_mix) {
            diff_fused<<<dim3(8, 8 * Lt), dim3(256), 0, stream>>>(
                gm, adpT, h, gcn_b + i * 32,
                bn_g + i * 32, bn_b + i * 32, bn_m + i * 32, bn_v + i * 32, t0, Lt);
        }
    }

    skip_mfma<<<dim3(2, 16, 16), dim3(256), 0, stream>>>(g12, wcat, sbcat, skipT);
    end1_mfma<<<dim3(8, 8, 16), dim3(256), 0, stream>>>(skipT, e1wb, e1b, y1);
    end2_kernel<<<dim3(8, 16), dim3(256), 0, stream>>>(y1, e2w, e2b, out);
}

// Round 12
// 365.125 us; speedup vs baseline: 1.1020x; 1.0741x over previous
//
#include <hip/hip_runtime.h>
#include <math.h>

// GraphWaveNet forward, MI355X. Round 12: tcn weight loads de-scattered.
// R11 tcn loaded A-frags with 256B lane stride (32 lines/instr, ~1024 L1
// transactions/wave). prep now repacks tcn_w+gcn_w into MFMA-frag order
// (bf16, [(q*64+lane)*8+j]) so each frag is one coalesced 16B load.
// Numerically bit-identical (same f2bf rounding, done once in prep).
// Everything else = R11 (diff 32x32x16 64x128 swizzled, layer-7 diff dropped).

#define NBATCH 16
#define LLEN 13
#define NNODE 1024

typedef __attribute__((ext_vector_type(8))) short bf16x8;
typedef __attribute__((ext_vector_type(4))) float f32x4;
typedef __attribute__((ext_vector_type(16))) float f32x16;

#define GLOAD16(gp, lp) __builtin_amdgcn_global_load_lds( \
    (const __attribute__((address_space(1))) void*)(gp), \
    (__attribute__((address_space(3))) void*)(lp), 16, 0, 0)

static __device__ inline short f2bf(float x) {
    union { float f; unsigned u; } v; v.f = x;
    unsigned r = v.u + 0x7FFFu + ((v.u >> 16) & 1u);
    return (short)(r >> 16);
}
static __device__ inline float bf2f(short x) {
    union { unsigned u; float f; } v; v.u = ((unsigned)(unsigned short)x) << 16;
    return v.f;
}
static __device__ inline unsigned pack2bf(float lo, float hi) {
    return (unsigned)(unsigned short)f2bf(lo) | ((unsigned)(unsigned short)f2bf(hi) << 16);
}

// ---------------- prep: adp stats | start conv | weight repack ---------------
// blocks [0,1024): stats; [1024,1856): start; [1856,2624): skip/e1 repack;
// [2624,2720): tcn/gcn frag repack.
__global__ __launch_bounds__(256) void prep_kernel(
        const float* __restrict__ emb, const float* __restrict__ x,
        const float* __restrict__ start_w, const float* __restrict__ start_b,
        const float* __restrict__ skip_w, const float* __restrict__ skip_b,
        const float* __restrict__ e1w, const float* __restrict__ tcn_w,
        const float* __restrict__ gcn_w,
        float* __restrict__ mx, float* __restrict__ inv, float* __restrict__ h,
        short* __restrict__ wcat, float* __restrict__ sbcat, short* __restrict__ e1wb,
        short* __restrict__ wtcn, short* __restrict__ wgcn) {
    int bid = blockIdx.x;
    int tid = threadIdx.x;
    if (bid < 1024) {
        int v = bid;
        __shared__ float red[256];
        float ev[10];
#pragma unroll
        for (int k = 0; k < 10; ++k) ev[k] = emb[v * 10 + k];
        float sc[4];
#pragma unroll
        for (int j = 0; j < 4; ++j) {
            int w = tid + j * 256;
            float s = 0.f;
#pragma unroll
            for (int k = 0; k < 10; ++k) s += ev[k] * emb[w * 10 + k];
            sc[j] = fmaxf(s, 0.f);
        }
        float m = fmaxf(fmaxf(sc[0], sc[1]), fmaxf(sc[2], sc[3]));
        red[tid] = m;
        __syncthreads();
        for (int s = 128; s > 0; s >>= 1) {
            if (tid < s) red[tid] = fmaxf(red[tid], red[tid + s]);
            __syncthreads();
        }
        m = red[0];
        __syncthreads();
        float sum = 0.f;
#pragma unroll
        for (int j = 0; j < 4; ++j) sum += __expf(sc[j] - m);
        red[tid] = sum;
        __syncthreads();
        for (int s = 128; s > 0; s >>= 1) {
            if (tid < s) red[tid] += red[tid + s];
            __syncthreads();
        }
        if (tid == 0) { mx[v] = m; inv[v] = 1.f / red[0]; }
    } else if (bid < 1856) {
        int it = (bid - 1024) * 256 + tid;
        int n = it & 1023, rest = it >> 10;
        int t = rest % 13, b = rest / 13;
        float2 xv = *(const float2*)(x + (size_t)it * 2);
#pragma unroll
        for (int r = 0; r < 32; ++r)
            h[((b * 32 + r) * 13 + t) * 1024 + n] =
                start_w[r * 2] * xv.x + start_w[r * 2 + 1] * xv.y + start_b[r];
    } else if (bid < 2624) {
        int idx = (bid - 1856) * 256 + tid;
        if (idx < 65536) {
            int s = idx >> 8, k = idx & 255, i = k >> 5, c = k & 31;
            wcat[idx] = f2bf(skip_w[(i * 256 + s) * 32 + c]);
        } else {
            int j = idx - 65536;
            e1wb[j] = f2bf(e1w[j]);
        }
        if (idx < 256) {
            float s = 0.f;
#pragma unroll
            for (int i = 0; i < 8; ++i) s += skip_b[i * 256 + idx];
            sbcat[idx] = s;
        }
    } else {
        int idx = (bid - 2624) * 256 + tid;   // < 24576
        if (idx < 16384) {
            // wtcn[((li*4+q)*64+lane)*8+j] = bf16(tcn_w[li][m][c][tap])
            int j = idx & 7, lane = (idx >> 3) & 63, q = (idx >> 9) & 3, li = idx >> 11;
            int m = lane & 31, hw = lane >> 5;
            int k = q * 16 + hw * 8 + j;
            int tap = k >> 5, c = k & 31;
            wtcn[idx] = f2bf(tcn_w[li * 2048 + (m * 32 + c) * 2 + tap]);
        } else {
            int idx2 = idx - 16384;
            // wgcn[((li*2+q)*64+lane)*8+j] = bf16(gcn_w[li][m][k])
            int j = idx2 & 7, lane = (idx2 >> 3) & 63, q = (idx2 >> 9) & 1, li = idx2 >> 10;
            int m = lane & 31, hw = lane >> 5;
            int k = q * 16 + hw * 8 + j;
            wgcn[idx2] = f2bf(gcn_w[li * 1024 + m * 32 + k]);
        }
    }
}

// ---------------- adpT[w][v] = softmax_v(relu(E E^T))[v][w] bf16 ------------
__global__ void adpT_kernel(const float* __restrict__ emb, const float* __restrict__ mx,
                            const float* __restrict__ inv, short* __restrict__ adpT) {
    int w = blockIdx.x;
    int tid = threadIdx.x;
    __shared__ float ew[10];
    if (tid < 10) ew[tid] = emb[w * 10 + tid];
    __syncthreads();
#pragma unroll
    for (int j = 0; j < 4; ++j) {
        int v = tid + j * 256;
        float s = 0.f;
#pragma unroll
        for (int k = 0; k < 10; ++k) s += ew[k] * emb[v * 10 + k];
        s = fmaxf(s, 0.f);
        adpT[w * 1024 + v] = f2bf(__expf(s - mx[v]) * inv[v]);
    }
}

// ---------------- TCN as MFMA: conv+gate(+mix) -> gm bf16 --------------------
__global__ __launch_bounds__(256) void tcn_mfma(
        const float* __restrict__ h, short* __restrict__ gm,
        short* __restrict__ g12,
        const short* __restrict__ wf, const float* __restrict__ bias,
        const short* __restrict__ gf,
        int d, int t0, int Lt, int li, int do_mix) {
    int tid = threadIdx.x;
    int wave = tid >> 6, lane = tid & 63;
    int m = lane & 31, hw = lane >> 5;
    int tt = blockIdx.y, t = t0 + tt, b = blockIdx.z;
    int n = blockIdx.x * 128 + wave * 32 + m;

    bf16x8 afrag[4];
#pragma unroll
    for (int q = 0; q < 4; ++q)
        afrag[q] = *(const bf16x8*)(wf + (((q << 6) + lane) << 3));
    bf16x8 bfrag[4];
#pragma unroll
    for (int q = 0; q < 4; ++q) {
        int kbase = q * 16 + hw * 8;
        int tap = kbase >> 5, c0 = kbase & 31;
        int tc = tap ? t : (t - d);
        const float* hb = h + (((size_t)((b * 32 + c0) * 13 + tc)) << 10) + n;
        bf16x8 fr;
#pragma unroll
        for (int j = 0; j < 8; ++j) fr[j] = f2bf(hb[(size_t)j * 13 * 1024]);
        bfrag[q] = fr;
    }
    f32x16 conv = {};
#pragma unroll
    for (int q = 0; q < 4; ++q)
        conv = __builtin_amdgcn_mfma_f32_32x32x16_bf16(afrag[q], bfrag[q], conv, 0, 0, 0);

    float gv[16];
#pragma unroll
    for (int r = 0; r < 16; ++r) {
        int o0 = (r & 3) + 8 * (r >> 2);
        float bv = hw ? bias[o0 + 4] : bias[o0];
        float a = conv[r] + bv;
        a = fminf(fmaxf(a, -25.f), 25.f);
        float e = __expf(-a), e2 = e * e;
        gv[r] = (1.f - e2) / ((1.f + e2) * (1.f + e));  // tanh(a)*sigmoid(a)
    }
    if (tt == Lt - 1) {  // t == 12: stash gated output for the skip GEMM
        short* gp = g12 + (((size_t)((b << 10) + n)) << 8) + li * 32;
#pragma unroll
        for (int r = 0; r < 16; ++r) {
            int o = (r & 3) + 8 * (r >> 2) + 4 * hw;
            gp[o] = f2bf(gv[r]);
        }
    }
    if (!do_mix) return;   // layer 7: gm/diffusion output is dead code

    unsigned pr[8], sp[8];
#pragma unroll
    for (int i = 0; i < 8; ++i) {
        pr[i] = pack2bf(gv[2 * i], gv[2 * i + 1]);
        sp[i] = (unsigned)__shfl_xor((int)pr[i], 32);
    }
    bf16x8 mfrag[2];
#pragma unroll
    for (int q = 0; q < 2; ++q) {
        union { unsigned u[4]; bf16x8 v; } tmpu;
        tmpu.u[0] = hw ? sp[q * 4 + 2] : pr[q * 4 + 0];
        tmpu.u[1] = hw ? sp[q * 4 + 3] : pr[q * 4 + 1];
        tmpu.u[2] = hw ? pr[q * 4 + 2] : sp[q * 4 + 0];
        tmpu.u[3] = hw ? pr[q * 4 + 3] : sp[q * 4 + 1];
        mfrag[q] = tmpu.v;
    }
    bf16x8 gwfrag[2];
#pragma unroll
    for (int q = 0; q < 2; ++q)
        gwfrag[q] = *(const bf16x8*)(gf + (((q << 6) + lane) << 3));
    f32x16 mix = {};
    mix = __builtin_amdgcn_mfma_f32_32x32x16_bf16(gwfrag[0], mfrag[0], mix, 0, 0, 0);
    mix = __builtin_amdgcn_mfma_f32_32x32x16_bf16(gwfrag[1], mfrag[1], mix, 0, 0, 0);
#pragma unroll
    for (int r = 0; r < 16; ++r) {
        int o2 = (r & 3) + 8 * (r >> 2) + 4 * hw;
        gm[(((size_t)((b * 32 + o2) * Lt + tt)) << 10) + n] = f2bf(mix[r]);
    }
}

// ======== 64x128 MFMA tile, 32x32x16 path (diff) ============================
template <int KLEN>
static __device__ __forceinline__ void mfma_tile32(
        const short* __restrict__ Abase, int strideA,
        const short* __restrict__ Bbase, int strideB,
        short* As, short* Bs, int tid, f32x16 acc[2]) {
    int wave = tid >> 6, lane = tid & 63;
    const short* srcA[2]; short* dstA[2];
    const short* srcB[4]; short* dstB[4];
#pragma unroll
    for (int j = 0; j < 2; ++j) {
        int slot = j * 256 + wave * 64 + lane;
        int row = slot >> 3, pp = slot & 7;
        int col = (pp ^ ((row >> 1) & 7)) * 8;
        srcA[j] = Abase + (size_t)row * strideA + col;
        dstA[j] = As + slot * 8;
    }
#pragma unroll
    for (int j = 0; j < 4; ++j) {
        int slot = j * 256 + wave * 64 + lane;
        int row = slot >> 3, pp = slot & 7;
        int col = (pp ^ ((row >> 1) & 7)) * 8;
        srcB[j] = Bbase + (size_t)row * strideB + col;
        dstB[j] = Bs + slot * 8;
    }
    int wm = (wave & 1) * 32, wn = (wave >> 1) * 64;
    int m32 = lane & 31, hw = lane >> 5;
    const short* paw = As + (wm + m32) * 64;
    int aswz = ((wm + m32) >> 1) & 7;
    const short* pb0 = Bs + (wn + m32) * 64;
    int bswz0 = ((wn + m32) >> 1) & 7;
    const short* pb1 = Bs + (wn + 32 + m32) * 64;
    int bswz1 = ((wn + 32 + m32) >> 1) & 7;
#pragma unroll 1
    for (int kk = 0; kk < KLEN; kk += 64) {
#pragma unroll
        for (int j = 0; j < 2; ++j) GLOAD16(srcA[j] + kk, dstA[j]);
#pragma unroll
        for (int j = 0; j < 4; ++j) GLOAD16(srcB[j] + kk, dstB[j]);
        __syncthreads();
#pragma unroll
        for (int ks = 0; ks < 4; ++ks) {
            int p = ks * 2 + hw;
            bf16x8 a = *(const bf16x8*)(paw + ((p ^ aswz) << 3));
            bf16x8 b0v = *(const bf16x8*)(pb0 + ((p ^ bswz0) << 3));
            bf16x8 b1v = *(const bf16x8*)(pb1 + ((p ^ bswz1) << 3));
            acc[0] = __builtin_amdgcn_mfma_f32_32x32x16_bf16(a, b0v, acc[0], 0, 0, 0);
            acc[1] = __builtin_amdgcn_mfma_f32_32x32x16_bf16(a, b1v, acc[1], 0, 0, 0);
        }
        __syncthreads();
    }
}

// ======== 64x128 MFMA tile, 16x16x32 path (skip/end1, proven) ===============
template <int KLEN>
static __device__ __forceinline__ void mfma_tile(
        const short* __restrict__ Abase, int strideA,
        const short* __restrict__ Bbase, int strideB,
        short* As, short* Bs, int tid, f32x4 acc[2][4]) {
    int wave = tid >> 6, lane = tid & 63;
    const short* srcA[2]; short* dstA[2];
    const short* srcB[4]; short* dstB[4];
#pragma unroll
    for (int j = 0; j < 2; ++j) {
        int slot = j * 256 + wave * 64 + lane;
        int row = slot >> 3, pp = slot & 7;
        int col = (pp ^ ((row >> 1) & 7)) * 8;
        srcA[j] = Abase + (size_t)row * strideA + col;
        dstA[j] = As + slot * 8;
    }
#pragma unroll
    for (int j = 0; j < 4; ++j) {
        int slot = j * 256 + wave * 64 + lane;
        int row = slot >> 3, pp = slot & 7;
        int col = (pp ^ ((row >> 1) & 7)) * 8;
        srcB[j] = Bbase + (size_t)row * strideB + col;
        dstB[j] = Bs + slot * 8;
    }
    int wm = (wave & 1) * 32, wn = (wave >> 1) * 64;
    int quad = lane >> 4, lrow = lane & 15;
    const short* paw = As + (wm + lrow) * 64;
    const short* pbw = Bs + (wn + lrow) * 64;
    int off0 = ((quad) ^ ((lrow >> 1) & 7)) * 8;
    int off1 = ((4 + quad) ^ ((lrow >> 1) & 7)) * 8;
#pragma unroll 1
    for (int kk = 0; kk < KLEN; kk += 64) {
#pragma unroll
        for (int j = 0; j < 2; ++j) GLOAD16(srcA[j] + kk, dstA[j]);
#pragma unroll
        for (int j = 0; j < 4; ++j) GLOAD16(srcB[j] + kk, dstB[j]);
        __syncthreads();
#pragma unroll
        for (int ks = 0; ks < 2; ++ks) {
            int off = ks ? off1 : off0;
            bf16x8 a[2], b[4];
#pragma unroll
            for (int i = 0; i < 2; ++i) a[i] = *(const bf16x8*)(paw + i * 16 * 64 + off);
#pragma unroll
            for (int i = 0; i < 4; ++i) b[i] = *(const bf16x8*)(pbw + i * 16 * 64 + off);
#pragma unroll
            for (int mi = 0; mi < 2; ++mi)
#pragma unroll
                for (int ni = 0; ni < 4; ++ni)
                    acc[mi][ni] = __builtin_amdgcn_mfma_f32_16x16x32_bf16(a[mi], b[ni], acc[mi][ni], 0, 0, 0);
        }
        __syncthreads();
    }
}

// ---------------- diffusion MFMA (32x32x16) + fused gcn epilogue -------------
__global__ __launch_bounds__(256) void diff_fused(const short* __restrict__ gm,
                                                  const short* __restrict__ adpT,
                                                  float* __restrict__ h,
                                                  const float* __restrict__ gb,
                                                  const float* __restrict__ bng,
                                                  const float* __restrict__ bnb,
                                                  const float* __restrict__ bnm,
                                                  const float* __restrict__ bnv,
                                                  int t0, int Lt) {
    __shared__ __align__(16) short As[64 * 64];
    __shared__ __align__(16) short Bs[128 * 64];
    __shared__ float sgb[32], sinv[32], smean[32], sbeta[32];
    int tid = threadIdx.x;
    int n0 = blockIdx.x * 128;
    int m0 = blockIdx.y * 64;
    if (tid < 32) {
        sgb[tid] = gb[tid];
        sinv[tid] = bng[tid] * rsqrtf(bnv[tid] + 1e-5f);
        smean[tid] = bnm[tid];
        sbeta[tid] = bnb[tid];
    }
    f32x16 acc[2] = {};
    mfma_tile32<1024>(gm + ((size_t)m0 << 10), 1024,
                      adpT + ((size_t)n0 << 10), 1024, As, Bs, tid, acc);
    int wave = tid >> 6, lane = tid & 63;
    int wm = (wave & 1) * 32, wn = (wave >> 1) * 64;
    int m32 = lane & 31, hw = lane >> 5;
#pragma unroll
    for (int nh = 0; nh < 2; ++nh) {
#pragma unroll
        for (int r = 0; r < 16; ++r) {
            int m = m0 + wm + (r & 3) + 8 * (r >> 2) + 4 * hw;
            unsigned bc = (unsigned)m / (unsigned)Lt;
            int tt = m - (int)bc * Lt;
            int c = bc & 31;
            float* crow = h + (((size_t)(bc * LLEN + t0 + tt)) << 10) + n0 + wn + nh * 32 + m32;
            float v = fmaxf(acc[nh][r] + sgb[c], 0.f) + *crow;
            *crow = (v - smean[c]) * sinv[c] + sbeta[c];
        }
    }
}

// ---------------- skip GEMM (64x128): skipT = relu(Wcat @ g12 + sbcat) ------
__global__ __launch_bounds__(256) void skip_mfma(const short* __restrict__ g12,
                                                 const short* __restrict__ wcat,
                                                 const float* __restrict__ sbcat,
                                                 short* __restrict__ skipT) {
    __shared__ __align__(16) short As[64 * 64];
    __shared__ __align__(16) short Bs[128 * 64];
    int tid = threadIdx.x;
    int s0 = blockIdx.x * 128;
    int m0 = blockIdx.y * 64;
    int b = blockIdx.z;
    f32x4 acc[2][4] = {};
    mfma_tile<256>(g12 + (((size_t)((b << 10) + m0)) << 8), 256,
                   wcat + ((size_t)s0 << 8), 256, As, Bs, tid, acc);
    int wave = tid >> 6, lane = tid & 63;
    int wm = (wave & 1) * 32, wn = (wave >> 1) * 64;
    int quad = lane >> 4, lrow = lane & 15;
#pragma unroll
    for (int mi = 0; mi < 2; ++mi) {
#pragma unroll
        for (int r = 0; r < 4; ++r) {
            int m = m0 + wm + mi * 16 + quad * 4 + r;
            short* crow = skipT + (((size_t)((b << 10) + m)) << 8) + s0 + wn + lrow;
#pragma unroll
            for (int ni = 0; ni < 4; ++ni) {
                int col = s0 + wn + lrow + ni * 16;
                crow[ni * 16] = f2bf(fmaxf(acc[mi][ni][r] + sbcat[col], 0.f));
            }
        }
    }
}

// ---------------- end1 (64x128): y1 = relu(e1w @ skipT + e1b) ----------------
__global__ __launch_bounds__(256) void end1_mfma(const short* __restrict__ skipT,
                                                 const short* __restrict__ e1wb,
                                                 const float* __restrict__ e1b,
                                                 short* __restrict__ y1) {
    __shared__ __align__(16) short As[64 * 64];
    __shared__ __align__(16) short Bs[128 * 64];
    int tid = threadIdx.x;
    int n0 = blockIdx.x * 128;
    int e0 = blockIdx.y * 64;
    int b = blockIdx.z;
    f32x4 acc[2][4] = {};
    mfma_tile<256>(e1wb + ((size_t)e0 << 8), 256,
                   skipT + (((size_t)((b << 10) + n0)) << 8), 256, As, Bs, tid, acc);
    int wave = tid >> 6, lane = tid & 63;
    int wm = (wave & 1) * 32, wn = (wave >> 1) * 64;
    int quad = lane >> 4, lrow = lane & 15;
#pragma unroll
    for (int mi = 0; mi < 2; ++mi) {
#pragma unroll
        for (int r = 0; r < 4; ++r) {
            int e = e0 + wm + mi * 16 + quad * 4 + r;
            float bv = e1b[e];
            short* crow = y1 + (((size_t)(b * 512 + e)) << 10) + n0 + wn + lrow;
#pragma unroll
            for (int ni = 0; ni < 4; ++ni)
                crow[ni * 16] = f2bf(fmaxf(acc[mi][ni][r] + bv, 0.f));
        }
    }
}

// ---------------- end2: out[b,n,o] = W2 @ y1 + b2 (parallel e-split) --------
__global__ __launch_bounds__(256) void end2_kernel(const short* __restrict__ y1,
                                                   const float* __restrict__ w2,
                                                   const float* __restrict__ b2,
                                                   float* __restrict__ out) {
    __shared__ float sw[12][512];
    __shared__ float ps[4][12][128];
    int tid = threadIdx.x;
    for (int idx = tid; idx < 6144; idx += 256) sw[idx >> 9][idx & 511] = w2[idx];
    __syncthreads();
    int n0 = blockIdx.x * 128;
    int bb = blockIdx.y;
    int nl = (tid & 63) * 2;
    int ec = tid >> 6;
    float acc0[12], acc1[12];
#pragma unroll
    for (int o = 0; o < 12; ++o) { acc0[o] = 0.f; acc1[o] = 0.f; }
    const short* yb = y1 + (((size_t)(bb * 512 + ec * 128)) << 10) + n0 + nl;
    for (int e = 0; e < 128; ++e) {
        ushort2 yv = *(const ushort2*)(yb + ((size_t)e << 10));
        float v0 = bf2f((short)yv.x), v1 = bf2f((short)yv.y);
        const float* we = &sw[0][ec * 128 + e];
#pragma unroll
        for (int o = 0; o < 12; ++o) {
            float wv = we[o * 512];
            acc0[o] += wv * v0;
            acc1[o] += wv * v1;
        }
    }
#pragma unroll
    for (int o = 0; o < 12; ++o) {
        ps[ec][o][nl] = acc0[o];
        ps[ec][o][nl + 1] = acc1[o];
    }
    __syncthreads();
    for (int idx = tid; idx < 1536; idx += 256) {
        int o = idx >> 7, nn = idx & 127;
        float s = b2[o] + ps[0][o][nn] + ps[1][o][nn] + ps[2][o][nn] + ps[3][o][nn];
        out[((size_t)(bb * NNODE + nn + n0)) * 12 + o] = s;
    }
}

extern "C" void kernel_launch(void* const* d_in, const int* in_sizes, int n_in,
                              void* d_out, int out_size, void* d_ws, size_t ws_size,
                              hipStream_t stream) {
    const float* x       = (const float*)d_in[0];
    const float* emb     = (const float*)d_in[1];
    const float* start_w = (const float*)d_in[2];
    const float* start_b = (const float*)d_in[3];
    const float* tcn_w   = (const float*)d_in[4];
    const float* tcn_b   = (const float*)d_in[5];
    const float* skip_w  = (const float*)d_in[6];
    const float* skip_b  = (const float*)d_in[7];
    const float* gcn_w   = (const float*)d_in[8];
    const float* gcn_b   = (const float*)d_in[9];
    const float* bn_g    = (const float*)d_in[10];
    const float* bn_b    = (const float*)d_in[11];
    const float* bn_m    = (const float*)d_in[12];
    const float* bn_v    = (const float*)d_in[13];
    const float* e1w     = (const float*)d_in[14];
    const float* e1b     = (const float*)d_in[15];
    const float* e2w     = (const float*)d_in[16];
    const float* e2b     = (const float*)d_in[17];
    float* out = (float*)d_out;

    char* wsb = (char*)d_ws;
    short* adpT  = (short*)(wsb);                    // 2,097,152
    float* mx    = (float*)(wsb + 2097152u);         // 4,096
    float* inv   = (float*)(wsb + 2101248u);         // 4,096
    float* h     = (float*)(wsb + 2105344u);         // 27,262,976
    short* gm    = (short*)(wsb + 29368320u);        // 12,582,912 (max Lt=12)
    short* g12   = (short*)(wsb + 41951232u);        // 8,388,608
    short* wcat  = (short*)(wsb + 50339840u);        // 131,072
    float* sbcat = (float*)(wsb + 50470912u);        // 1,024
    short* e1wb  = (short*)(wsb + 50471936u);        // 262,144
    short* skipT = (short*)(wsb + 50734080u);        // 8,388,608
    short* y1    = (short*)(wsb + 59122688u);        // 16,777,216
    short* wtcn  = (short*)(wsb + 75899904u);        // 32,768
    short* wgcn  = (short*)(wsb + 75932672u);        // 16,384

    prep_kernel<<<dim3(2720), dim3(256), 0, stream>>>(
        emb, x, start_w, start_b, skip_w, skip_b, e1w, tcn_w, gcn_w,
        mx, inv, h, wcat, sbcat, e1wb, wtcn, wgcn);
    adpT_kernel<<<dim3(1024), dim3(256), 0, stream>>>(emb, mx, inv, adpT);

    const int dil[8] = {1, 2, 1, 2, 1, 2, 1, 2};
    const int t0s[8] = {1, 3, 4, 6, 7, 9, 10, 12};
    for (int i = 0; i < 8; ++i) {
        int d = dil[i];
        int t0 = t0s[i];
        int Lt = 13 - t0;
        int do_mix = (i < 7) ? 1 : 0;
        tcn_mfma<<<dim3(8, Lt, 16), dim3(256), 0, stream>>>(
            h, gm, g12, wtcn + i * 2048, tcn_b + i * 32, wgcn + i * 1024,
            d, t0, Lt, i, do_mix);
        if (do_mix) {
            diff_fused<<<dim3(8, 8 * Lt), dim3(256), 0, stream>>>(
                gm, adpT, h, gcn_b + i * 32,
                bn_g + i * 32, bn_b + i * 32, bn_m + i * 32, bn_v + i * 32, t0, Lt);
        }
    }

    skip_mfma<<<dim3(2, 16, 16), dim3(256), 0, stream>>>(g12, wcat, sbcat, skipT);
    end1_mfma<<<dim3(8, 8, 16), dim3(256), 0, stream>>>(skipT, e1wb, e1b, y1);
    end2_kernel<<<dim3(8, 16), dim3(256), 0, stream>>>(y1, e2w, e2b, out);
}

// Round 13
// 353.371 us; speedup vs baseline: 1.1387x; 1.0333x over previous
//
#include <hip/hip_runtime.h>
#include <math.h>

// GraphWaveNet forward, MI355X. Round 13: diff BK 64->128.
// diff is ~50% of runtime; its K-loop paid 2 barriers x 16 iters (m97-style
// vmcnt(0) drain each). BK=128: 8 iters, 16 MFMA-32/barrier, LDS 48KB keeps
// 3 blocks/CU (the current grid-limited residency) unlike m132's 64KB case.
// K accumulation order unchanged -> bit-identical numerics vs R12.
// Everything else = R12 (tcn frag-packed weights, layer-7 diff dropped).

#define NBATCH 16
#define LLEN 13
#define NNODE 1024

typedef __attribute__((ext_vector_type(8))) short bf16x8;
typedef __attribute__((ext_vector_type(4))) float f32x4;
typedef __attribute__((ext_vector_type(16))) float f32x16;

#define GLOAD16(gp, lp) __builtin_amdgcn_global_load_lds( \
    (const __attribute__((address_space(1))) void*)(gp), \
    (__attribute__((address_space(3))) void*)(lp), 16, 0, 0)

static __device__ inline short f2bf(float x) {
    union { float f; unsigned u; } v; v.f = x;
    unsigned r = v.u + 0x7FFFu + ((v.u >> 16) & 1u);
    return (short)(r >> 16);
}
static __device__ inline float bf2f(short x) {
    union { unsigned u; float f; } v; v.u = ((unsigned)(unsigned short)x) << 16;
    return v.f;
}
static __device__ inline unsigned pack2bf(float lo, float hi) {
    return (unsigned)(unsigned short)f2bf(lo) | ((unsigned)(unsigned short)f2bf(hi) << 16);
}

// ---------------- prep: adp stats | start conv | weight repack ---------------
__global__ __launch_bounds__(256) void prep_kernel(
        const float* __restrict__ emb, const float* __restrict__ x,
        const float* __restrict__ start_w, const float* __restrict__ start_b,
        const float* __restrict__ skip_w, const float* __restrict__ skip_b,
        const float* __restrict__ e1w, const float* __restrict__ tcn_w,
        const float* __restrict__ gcn_w,
        float* __restrict__ mx, float* __restrict__ inv, float* __restrict__ h,
        short* __restrict__ wcat, float* __restrict__ sbcat, short* __restrict__ e1wb,
        short* __restrict__ wtcn, short* __restrict__ wgcn) {
    int bid = blockIdx.x;
    int tid = threadIdx.x;
    if (bid < 1024) {
        int v = bid;
        __shared__ float red[256];
        float ev[10];
#pragma unroll
        for (int k = 0; k < 10; ++k) ev[k] = emb[v * 10 + k];
        float sc[4];
#pragma unroll
        for (int j = 0; j < 4; ++j) {
            int w = tid + j * 256;
            float s = 0.f;
#pragma unroll
            for (int k = 0; k < 10; ++k) s += ev[k] * emb[w * 10 + k];
            sc[j] = fmaxf(s, 0.f);
        }
        float m = fmaxf(fmaxf(sc[0], sc[1]), fmaxf(sc[2], sc[3]));
        red[tid] = m;
        __syncthreads();
        for (int s = 128; s > 0; s >>= 1) {
            if (tid < s) red[tid] = fmaxf(red[tid], red[tid + s]);
            __syncthreads();
        }
        m = red[0];
        __syncthreads();
        float sum = 0.f;
#pragma unroll
        for (int j = 0; j < 4; ++j) sum += __expf(sc[j] - m);
        red[tid] = sum;
        __syncthreads();
        for (int s = 128; s > 0; s >>= 1) {
            if (tid < s) red[tid] += red[tid + s];
            __syncthreads();
        }
        if (tid == 0) { mx[v] = m; inv[v] = 1.f / red[0]; }
    } else if (bid < 1856) {
        int it = (bid - 1024) * 256 + tid;
        int n = it & 1023, rest = it >> 10;
        int t = rest % 13, b = rest / 13;
        float2 xv = *(const float2*)(x + (size_t)it * 2);
#pragma unroll
        for (int r = 0; r < 32; ++r)
            h[((b * 32 + r) * 13 + t) * 1024 + n] =
                start_w[r * 2] * xv.x + start_w[r * 2 + 1] * xv.y + start_b[r];
    } else if (bid < 2624) {
        int idx = (bid - 1856) * 256 + tid;
        if (idx < 65536) {
            int s = idx >> 8, k = idx & 255, i = k >> 5, c = k & 31;
            wcat[idx] = f2bf(skip_w[(i * 256 + s) * 32 + c]);
        } else {
            int j = idx - 65536;
            e1wb[j] = f2bf(e1w[j]);
        }
        if (idx < 256) {
            float s = 0.f;
#pragma unroll
            for (int i = 0; i < 8; ++i) s += skip_b[i * 256 + idx];
            sbcat[idx] = s;
        }
    } else {
        int idx = (bid - 2624) * 256 + tid;   // < 24576
        if (idx < 16384) {
            int j = idx & 7, lane = (idx >> 3) & 63, q = (idx >> 9) & 3, li = idx >> 11;
            int m = lane & 31, hw = lane >> 5;
            int k = q * 16 + hw * 8 + j;
            int tap = k >> 5, c = k & 31;
            wtcn[idx] = f2bf(tcn_w[li * 2048 + (m * 32 + c) * 2 + tap]);
        } else {
            int idx2 = idx - 16384;
            int j = idx2 & 7, lane = (idx2 >> 3) & 63, q = (idx2 >> 9) & 1, li = idx2 >> 10;
            int m = lane & 31, hw = lane >> 5;
            int k = q * 16 + hw * 8 + j;
            wgcn[idx2] = f2bf(gcn_w[li * 1024 + m * 32 + k]);
        }
    }
}

// ---------------- adpT[w][v] = softmax_v(relu(E E^T))[v][w] bf16 ------------
__global__ void adpT_kernel(const float* __restrict__ emb, const float* __restrict__ mx,
                            const float* __restrict__ inv, short* __restrict__ adpT) {
    int w = blockIdx.x;
    int tid = threadIdx.x;
    __shared__ float ew[10];
    if (tid < 10) ew[tid] = emb[w * 10 + tid];
    __syncthreads();
#pragma unroll
    for (int j = 0; j < 4; ++j) {
        int v = tid + j * 256;
        float s = 0.f;
#pragma unroll
        for (int k = 0; k < 10; ++k) s += ew[k] * emb[v * 10 + k];
        s = fmaxf(s, 0.f);
        adpT[w * 1024 + v] = f2bf(__expf(s - mx[v]) * inv[v]);
    }
}

// ---------------- TCN as MFMA: conv+gate(+mix) -> gm bf16 --------------------
__global__ __launch_bounds__(256) void tcn_mfma(
        const float* __restrict__ h, short* __restrict__ gm,
        short* __restrict__ g12,
        const short* __restrict__ wf, const float* __restrict__ bias,
        const short* __restrict__ gf,
        int d, int t0, int Lt, int li, int do_mix) {
    int tid = threadIdx.x;
    int wave = tid >> 6, lane = tid & 63;
    int m = lane & 31, hw = lane >> 5;
    int tt = blockIdx.y, t = t0 + tt, b = blockIdx.z;
    int n = blockIdx.x * 128 + wave * 32 + m;

    bf16x8 afrag[4];
#pragma unroll
    for (int q = 0; q < 4; ++q)
        afrag[q] = *(const bf16x8*)(wf + (((q << 6) + lane) << 3));
    bf16x8 bfrag[4];
#pragma unroll
    for (int q = 0; q < 4; ++q) {
        int kbase = q * 16 + hw * 8;
        int tap = kbase >> 5, c0 = kbase & 31;
        int tc = tap ? t : (t - d);
        const float* hb = h + (((size_t)((b * 32 + c0) * 13 + tc)) << 10) + n;
        bf16x8 fr;
#pragma unroll
        for (int j = 0; j < 8; ++j) fr[j] = f2bf(hb[(size_t)j * 13 * 1024]);
        bfrag[q] = fr;
    }
    f32x16 conv = {};
#pragma unroll
    for (int q = 0; q < 4; ++q)
        conv = __builtin_amdgcn_mfma_f32_32x32x16_bf16(afrag[q], bfrag[q], conv, 0, 0, 0);

    float gv[16];
#pragma unroll
    for (int r = 0; r < 16; ++r) {
        int o0 = (r & 3) + 8 * (r >> 2);
        float bv = hw ? bias[o0 + 4] : bias[o0];
        float a = conv[r] + bv;
        a = fminf(fmaxf(a, -25.f), 25.f);
        float e = __expf(-a), e2 = e * e;
        gv[r] = (1.f - e2) / ((1.f + e2) * (1.f + e));  // tanh(a)*sigmoid(a)
    }
    if (tt == Lt - 1) {  // t == 12: stash gated output for the skip GEMM
        short* gp = g12 + (((size_t)((b << 10) + n)) << 8) + li * 32;
#pragma unroll
        for (int r = 0; r < 16; ++r) {
            int o = (r & 3) + 8 * (r >> 2) + 4 * hw;
            gp[o] = f2bf(gv[r]);
        }
    }
    if (!do_mix) return;   // layer 7: gm/diffusion output is dead code

    unsigned pr[8], sp[8];
#pragma unroll
    for (int i = 0; i < 8; ++i) {
        pr[i] = pack2bf(gv[2 * i], gv[2 * i + 1]);
        sp[i] = (unsigned)__shfl_xor((int)pr[i], 32);
    }
    bf16x8 mfrag[2];
#pragma unroll
    for (int q = 0; q < 2; ++q) {
        union { unsigned u[4]; bf16x8 v; } tmpu;
        tmpu.u[0] = hw ? sp[q * 4 + 2] : pr[q * 4 + 0];
        tmpu.u[1] = hw ? sp[q * 4 + 3] : pr[q * 4 + 1];
        tmpu.u[2] = hw ? pr[q * 4 + 2] : sp[q * 4 + 0];
        tmpu.u[3] = hw ? pr[q * 4 + 3] : sp[q * 4 + 1];
        mfrag[q] = tmpu.v;
    }
    bf16x8 gwfrag[2];
#pragma unroll
    for (int q = 0; q < 2; ++q)
        gwfrag[q] = *(const bf16x8*)(gf + (((q << 6) + lane) << 3));
    f32x16 mix = {};
    mix = __builtin_amdgcn_mfma_f32_32x32x16_bf16(gwfrag[0], mfrag[0], mix, 0, 0, 0);
    mix = __builtin_amdgcn_mfma_f32_32x32x16_bf16(gwfrag[1], mfrag[1], mix, 0, 0, 0);
#pragma unroll
    for (int r = 0; r < 16; ++r) {
        int o2 = (r & 3) + 8 * (r >> 2) + 4 * hw;
        gm[(((size_t)((b * 32 + o2) * Lt + tt)) << 10) + n] = f2bf(mix[r]);
    }
}

// ======== 64x128 MFMA tile, 32x32x16 path, BK=128 (diff) ====================
// LDS rows = 128 shorts (16 chunk positions); swizzle p ^ (row & 15).
template <int KLEN>
static __device__ __forceinline__ void mfma_tile32(
        const short* __restrict__ Abase, int strideA,
        const short* __restrict__ Bbase, int strideB,
        short* As, short* Bs, int tid, f32x16 acc[2]) {
    int wave = tid >> 6, lane = tid & 63;
    const short* srcA[4]; short* dstA[4];
    const short* srcB[8]; short* dstB[8];
#pragma unroll
    for (int j = 0; j < 4; ++j) {
        int slot = j * 256 + wave * 64 + lane;       // < 1024 (64 rows x 16)
        int row = slot >> 4, pp = slot & 15;
        int col = (pp ^ (row & 15)) * 8;
        srcA[j] = Abase + (size_t)row * strideA + col;
        dstA[j] = As + slot * 8;
    }
#pragma unroll
    for (int j = 0; j < 8; ++j) {
        int slot = j * 256 + wave * 64 + lane;       // < 2048 (128 rows x 16)
        int row = slot >> 4, pp = slot & 15;
        int col = (pp ^ (row & 15)) * 8;
        srcB[j] = Bbase + (size_t)row * strideB + col;
        dstB[j] = Bs + slot * 8;
    }
    int wm = (wave & 1) * 32, wn = (wave >> 1) * 64;
    int m32 = lane & 31, hw = lane >> 5;
    const short* paw = As + (wm + m32) * 128;
    int aswz = (wm + m32) & 15;
    const short* pb0 = Bs + (wn + m32) * 128;
    int bswz0 = (wn + m32) & 15;
    const short* pb1 = Bs + (wn + 32 + m32) * 128;
    int bswz1 = (wn + 32 + m32) & 15;
#pragma unroll 1
    for (int kk = 0; kk < KLEN; kk += 128) {
#pragma unroll
        for (int j = 0; j < 4; ++j) GLOAD16(srcA[j] + kk, dstA[j]);
#pragma unroll
        for (int j = 0; j < 8; ++j) GLOAD16(srcB[j] + kk, dstB[j]);
        __syncthreads();
#pragma unroll
        for (int ks = 0; ks < 8; ++ks) {
            int p = ks * 2 + hw;
            bf16x8 a = *(const bf16x8*)(paw + ((p ^ aswz) << 3));
            bf16x8 b0v = *(const bf16x8*)(pb0 + ((p ^ bswz0) << 3));
            bf16x8 b1v = *(const bf16x8*)(pb1 + ((p ^ bswz1) << 3));
            acc[0] = __builtin_amdgcn_mfma_f32_32x32x16_bf16(a, b0v, acc[0], 0, 0, 0);
            acc[1] = __builtin_amdgcn_mfma_f32_32x32x16_bf16(a, b1v, acc[1], 0, 0, 0);
        }
        __syncthreads();
    }
}

// ======== 64x128 MFMA tile, 16x16x32 path, BK=64 (skip/end1, proven) ========
template <int KLEN>
static __device__ __forceinline__ void mfma_tile(
        const short* __restrict__ Abase, int strideA,
        const short* __restrict__ Bbase, int strideB,
        short* As, short* Bs, int tid, f32x4 acc[2][4]) {
    int wave = tid >> 6, lane = tid & 63;
    const short* srcA[2]; short* dstA[2];
    const short* srcB[4]; short* dstB[4];
#pragma unroll
    for (int j = 0; j < 2; ++j) {
        int slot = j * 256 + wave * 64 + lane;
        int row = slot >> 3, pp = slot & 7;
        int col = (pp ^ ((row >> 1) & 7)) * 8;
        srcA[j] = Abase + (size_t)row * strideA + col;
        dstA[j] = As + slot * 8;
    }
#pragma unroll
    for (int j = 0; j < 4; ++j) {
        int slot = j * 256 + wave * 64 + lane;
        int row = slot >> 3, pp = slot & 7;
        int col = (pp ^ ((row >> 1) & 7)) * 8;
        srcB[j] = Bbase + (size_t)row * strideB + col;
        dstB[j] = Bs + slot * 8;
    }
    int wm = (wave & 1) * 32, wn = (wave >> 1) * 64;
    int quad = lane >> 4, lrow = lane & 15;
    const short* paw = As + (wm + lrow) * 64;
    const short* pbw = Bs + (wn + lrow) * 64;
    int off0 = ((quad) ^ ((lrow >> 1) & 7)) * 8;
    int off1 = ((4 + quad) ^ ((lrow >> 1) & 7)) * 8;
#pragma unroll 1
    for (int kk = 0; kk < KLEN; kk += 64) {
#pragma unroll
        for (int j = 0; j < 2; ++j) GLOAD16(srcA[j] + kk, dstA[j]);
#pragma unroll
        for (int j = 0; j < 4; ++j) GLOAD16(srcB[j] + kk, dstB[j]);
        __syncthreads();
#pragma unroll
        for (int ks = 0; ks < 2; ++ks) {
            int off = ks ? off1 : off0;
            bf16x8 a[2], b[4];
#pragma unroll
            for (int i = 0; i < 2; ++i) a[i] = *(const bf16x8*)(paw + i * 16 * 64 + off);
#pragma unroll
            for (int i = 0; i < 4; ++i) b[i] = *(const bf16x8*)(pbw + i * 16 * 64 + off);
#pragma unroll
            for (int mi = 0; mi < 2; ++mi)
#pragma unroll
                for (int ni = 0; ni < 4; ++ni)
                    acc[mi][ni] = __builtin_amdgcn_mfma_f32_16x16x32_bf16(a[mi], b[ni], acc[mi][ni], 0, 0, 0);
        }
        __syncthreads();
    }
}

// ---------------- diffusion MFMA (32x32x16, BK=128) + fused gcn epilogue -----
__global__ __launch_bounds__(256) void diff_fused(const short* __restrict__ gm,
                                                  const short* __restrict__ adpT,
                                                  float* __restrict__ h,
                                                  const float* __restrict__ gb,
                                                  const float* __restrict__ bng,
                                                  const float* __restrict__ bnb,
                                                  const float* __restrict__ bnm,
                                                  const float* __restrict__ bnv,
                                                  int t0, int Lt) {
    __shared__ __align__(16) short As[64 * 128];
    __shared__ __align__(16) short Bs[128 * 128];
    __shared__ float sgb[32], sinv[32], smean[32], sbeta[32];
    int tid = threadIdx.x;
    int n0 = blockIdx.x * 128;
    int m0 = blockIdx.y * 64;
    if (tid < 32) {
        sgb[tid] = gb[tid];
        sinv[tid] = bng[tid] * rsqrtf(bnv[tid] + 1e-5f);
        smean[tid] = bnm[tid];
        sbeta[tid] = bnb[tid];
    }
    f32x16 acc[2] = {};
    mfma_tile32<1024>(gm + ((size_t)m0 << 10), 1024,
                      adpT + ((size_t)n0 << 10), 1024, As, Bs, tid, acc);
    int wave = tid >> 6, lane = tid & 63;
    int wm = (wave & 1) * 32, wn = (wave >> 1) * 64;
    int m32 = lane & 31, hw = lane >> 5;
#pragma unroll
    for (int nh = 0; nh < 2; ++nh) {
#pragma unroll
        for (int r = 0; r < 16; ++r) {
            int m = m0 + wm + (r & 3) + 8 * (r >> 2) + 4 * hw;
            unsigned bc = (unsigned)m / (unsigned)Lt;
            int tt = m - (int)bc * Lt;
            int c = bc & 31;
            float* crow = h + (((size_t)(bc * LLEN + t0 + tt)) << 10) + n0 + wn + nh * 32 + m32;
            float v = fmaxf(acc[nh][r] + sgb[c], 0.f) + *crow;
            *crow = (v - smean[c]) * sinv[c] + sbeta[c];
        }
    }
}

// ---------------- skip GEMM (64x128): skipT = relu(Wcat @ g12 + sbcat) ------
__global__ __launch_bounds__(256) void skip_mfma(const short* __restrict__ g12,
                                                 const short* __restrict__ wcat,
                                                 const float* __restrict__ sbcat,
                                                 short* __restrict__ skipT) {
    __shared__ __align__(16) short As[64 * 64];
    __shared__ __align__(16) short Bs[128 * 64];
    int tid = threadIdx.x;
    int s0 = blockIdx.x * 128;
    int m0 = blockIdx.y * 64;
    int b = blockIdx.z;
    f32x4 acc[2][4] = {};
    mfma_tile<256>(g12 + (((size_t)((b << 10) + m0)) << 8), 256,
                   wcat + ((size_t)s0 << 8), 256, As, Bs, tid, acc);
    int wave = tid >> 6, lane = tid & 63;
    int wm = (wave & 1) * 32, wn = (wave >> 1) * 64;
    int quad = lane >> 4, lrow = lane & 15;
#pragma unroll
    for (int mi = 0; mi < 2; ++mi) {
#pragma unroll
        for (int r = 0; r < 4; ++r) {
            int m = m0 + wm + mi * 16 + quad * 4 + r;
            short* crow = skipT + (((size_t)((b << 10) + m)) << 8) + s0 + wn + lrow;
#pragma unroll
            for (int ni = 0; ni < 4; ++ni) {
                int col = s0 + wn + lrow + ni * 16;
                crow[ni * 16] = f2bf(fmaxf(acc[mi][ni][r] + sbcat[col], 0.f));
            }
        }
    }
}

// ---------------- end1 (64x128): y1 = relu(e1w @ skipT + e1b) ----------------
__global__ __launch_bounds__(256) void end1_mfma(const short* __restrict__ skipT,
                                                 const short* __restrict__ e1wb,
                                                 const float* __restrict__ e1b,
                                                 short* __restrict__ y1) {
    __shared__ __align__(16) short As[64 * 64];
    __shared__ __align__(16) short Bs[128 * 64];
    int tid = threadIdx.x;
    int n0 = blockIdx.x * 128;
    int e0 = blockIdx.y * 64;
    int b = blockIdx.z;
    f32x4 acc[2][4] = {};
    mfma_tile<256>(e1wb + ((size_t)e0 << 8), 256,
                   skipT + (((size_t)((b << 10) + n0)) << 8), 256, As, Bs, tid, acc);
    int wave = tid >> 6, lane = tid & 63;
    int wm = (wave & 1) * 32, wn = (wave >> 1) * 64;
    int quad = lane >> 4, lrow = lane & 15;
#pragma unroll
    for (int mi = 0; mi < 2; ++mi) {
#pragma unroll
        for (int r = 0; r < 4; ++r) {
            int e = e0 + wm + mi * 16 + quad * 4 + r;
            float bv = e1b[e];
            short* crow = y1 + (((size_t)(b * 512 + e)) << 10) + n0 + wn + lrow;
#pragma unroll
            for (int ni = 0; ni < 4; ++ni)
                crow[ni * 16] = f2bf(fmaxf(acc[mi][ni][r] + bv, 0.f));
        }
    }
}

// ---------------- end2: out[b,n,o] = W2 @ y1 + b2 (parallel e-split) --------
__global__ __launch_bounds__(256) void end2_kernel(const short* __restrict__ y1,
                                                   const float* __restrict__ w2,
                                                   const float* __restrict__ b2,
                                                   float* __restrict__ out) {
    __shared__ float sw[12][512];
    __shared__ float ps[4][12][128];
    int tid = threadIdx.x;
    for (int idx = tid; idx < 6144; idx += 256) sw[idx >> 9][idx & 511] = w2[idx];
    __syncthreads();
    int n0 = blockIdx.x * 128;
    int bb = blockIdx.y;
    int nl = (tid & 63) * 2;
    int ec = tid >> 6;
    float acc0[12], acc1[12];
#pragma unroll
    for (int o = 0; o < 12; ++o) { acc0[o] = 0.f; acc1[o] = 0.f; }
    const short* yb = y1 + (((size_t)(bb * 512 + ec * 128)) << 10) + n0 + nl;
    for (int e = 0; e < 128; ++e) {
        ushort2 yv = *(const ushort2*)(yb + ((size_t)e << 10));
        float v0 = bf2f((short)yv.x), v1 = bf2f((short)yv.y);
        const float* we = &sw[0][ec * 128 + e];
#pragma unroll
        for (int o = 0; o < 12; ++o) {
            float wv = we[o * 512];
            acc0[o] += wv * v0;
            acc1[o] += wv * v1;
        }
    }
#pragma unroll
    for (int o = 0; o < 12; ++o) {
        ps[ec][o][nl] = acc0[o];
        ps[ec][o][nl + 1] = acc1[o];
    }
    __syncthreads();
    for (int idx = tid; idx < 1536; idx += 256) {
        int o = idx >> 7, nn = idx & 127;
        float s = b2[o] + ps[0][o][nn] + ps[1][o][nn] + ps[2][o][nn] + ps[3][o][nn];
        out[((size_t)(bb * NNODE + nn + n0)) * 12 + o] = s;
    }
}

extern "C" void kernel_launch(void* const* d_in, const int* in_sizes, int n_in,
                              void* d_out, int out_size, void* d_ws, size_t ws_size,
                              hipStream_t stream) {
    const float* x       = (const float*)d_in[0];
    const float* emb     = (const float*)d_in[1];
    const float* start_w = (const float*)d_in[2];
    const float* start_b = (const float*)d_in[3];
    const float* tcn_w   = (const float*)d_in[4];
    const float* tcn_b   = (const float*)d_in[5];
    const float* skip_w  = (const float*)d_in[6];
    const float* skip_b  = (const float*)d_in[7];
    const float* gcn_w   = (const float*)d_in[8];
    const float* gcn_b   = (const float*)d_in[9];
    const float* bn_g    = (const float*)d_in[10];
    const float* bn_b    = (const float*)d_in[11];
    const float* bn_m    = (const float*)d_in[12];
    const float* bn_v    = (const float*)d_in[13];
    const float* e1w     = (const float*)d_in[14];
    const float* e1b     = (const float*)d_in[15];
    const float* e2w     = (const float*)d_in[16];
    const float* e2b     = (const float*)d_in[17];
    float* out = (float*)d_out;

    char* wsb = (char*)d_ws;
    short* adpT  = (short*)(wsb);                    // 2,097,152
    float* mx    = (float*)(wsb + 2097152u);         // 4,096
    float* inv   = (float*)(wsb + 2101248u);         // 4,096
    float* h     = (float*)(wsb + 2105344u);         // 27,262,976
    short* gm    = (short*)(wsb + 29368320u);        // 12,582,912 (max Lt=12)
    short* g12   = (short*)(wsb + 41951232u);        // 8,388,608
    short* wcat  = (short*)(wsb + 50339840u);        // 131,072
    float* sbcat = (float*)(wsb + 50470912u);        // 1,024
    short* e1wb  = (short*)(wsb + 50471936u);        // 262,144
    short* skipT = (short*)(wsb + 50734080u);        // 8,388,608
    short* y1    = (short*)(wsb + 59122688u);        // 16,777,216
    short* wtcn  = (short*)(wsb + 75899904u);        // 32,768
    short* wgcn  = (short*)(wsb + 75932672u);        // 16,384

    prep_kernel<<<dim3(2720), dim3(256), 0, stream>>>(
        emb, x, start_w, start_b, skip_w, skip_b, e1w, tcn_w, gcn_w,
        mx, inv, h, wcat, sbcat, e1wb, wtcn, wgcn);
    adpT_kernel<<<dim3(1024), dim3(256), 0, stream>>>(emb, mx, inv, adpT);

    const int dil[8] = {1, 2, 1, 2, 1, 2, 1, 2};
    const int t0s[8] = {1, 3, 4, 6, 7, 9, 10, 12};
    for (int i = 0; i < 8; ++i) {
        int d = dil[i];
        int t0 = t0s[i];
        int Lt = 13 - t0;
        int do_mix = (i < 7) ? 1 : 0;
        tcn_mfma<<<dim3(8, Lt, 16), dim3(256), 0, stream>>>(
            h, gm, g12, wtcn + i * 2048, tcn_b + i * 32, wgcn + i * 1024,
            d, t0, Lt, i, do_mix);
        if (do_mix) {
            diff_fused<<<dim3(8, 8 * Lt), dim3(256), 0, stream>>>(
                gm, adpT, h, gcn_b + i * 32,
                bn_g + i * 32, bn_b + i * 32, bn_m + i * 32, bn_v + i * 32, t0, Lt);
        }
    }

    skip_mfma<<<dim3(2, 16, 16), dim3(256), 0, stream>>>(g12, wcat, sbcat, skipT);
    end1_mfma<<<dim3(8, 8, 16), dim3(256), 0, stream>>>(skipT, e1wb, e1b, y1);
    end2_kernel<<<dim3(8, 16), dim3(256), 0, stream>>>(y1, e2w, e2b, out);
}